// Round 9
// baseline (191.047 us; speedup 1.0000x reference)
//
#include <hip/hip_runtime.h>
#include <math.h>

#define EPSV 1e-5f

// conv1 (3-tap, zero-pad) + relu at the 3 positions of one sample
__device__ __forceinline__ void conv3_relu(float x0, float x1, float x2,
                                           float wa, float wb, float wc, float bb,
                                           float& t0, float& t1, float& t2)
{
    t0 = fmaxf(fmaf(wb, x0, fmaf(wc, x1, bb)), 0.f);
    t1 = fmaxf(fmaf(wa, x0, fmaf(wb, x1, fmaf(wc, x2, bb))), 0.f);
    t2 = fmaxf(fmaf(wa, x1, fmaf(wb, x2, bb)), 0.f);
}

// ---------------------------------------------------------------------------
// R18 structure: 3 dispatches, but k_final is the EXACT R11-proven kernel
// (pure table loads, no inlined reductions, unroll 4, plain bounds, 40.6us).
// R17 showed the fin-prologue + unroll4 combo stalls pathologically
// (89.6us @ VALUBusy 27.7%; VALU-microseconds constant across R11/R12/R13/R17
// => same clock, pure schedule regression from prologue+body co-compilation).
// fin2 now runs as a LAST-BLOCK epilogue of k_stats2 (threadfence-reduction
// pattern: publish partials -> fence -> atomicAdd counter; last block alone
// reduces p2 -> BN2 -> fw1sT/c1 to global; other blocks exit, no spinning).
// Block 0 of k_stats2 dumps its fin1 results (sU/sC) to global for k_final.
// ---------------------------------------------------------------------------

// ---------------------------------------------------------------------------
// Pass 1: per-channel sum/sumsq of relu(conv1(x)+b1), 16 ch.
// Group-outer / sample-inner — ONE sW1[g] LDS read per 4-sample chunk.
// partials[block*32 + v]: v<16 sum, v>=16 sq
// ---------------------------------------------------------------------------
__global__ __launch_bounds__(256) void k_stats1(const float* __restrict__ x,
                                                const float* __restrict__ w1,
                                                const float* __restrict__ b1,
                                                float* __restrict__ partials,
                                                int B)
{
    __shared__ float4 sW1[16];
    int t = threadIdx.x;
    if (t < 16) sW1[t] = make_float4(w1[3*t], w1[3*t+1], w1[3*t+2], b1[t]);
    __syncthreads();

    float cur[32];   // [0,16): sum, [16,32): sq
#pragma unroll
    for (int i = 0; i < 32; ++i) cur[i] = 0.f;

    auto upd = [&](int g, float t0, float t1, float t2) {
        cur[g]      += t0 + t1 + t2;
        cur[16 + g]  = fmaf(t0, t0, fmaf(t1, t1, fmaf(t2, t2, cur[16 + g])));
    };

    auto accum1 = [&](float x0, float x1, float x2) {   // tail only
#pragma unroll
        for (int g = 0; g < 16; ++g) {
            float4 w = sW1[g];
            float t0, t1, t2;
            conv3_relu(x0, x1, x2, w.x, w.y, w.z, w.w, t0, t1, t2);
            upd(g, t0, t1, t2);
        }
    };

    int nchunk = (B + 3) >> 2;
    for (int ch = blockIdx.x * 256 + t; ch < nchunk; ch += gridDim.x * 256) {
        int s0 = ch << 2;
        if (s0 + 4 <= B) {
            const float4* xp = (const float4*)(x + (size_t)s0 * 3);
            float4 A = xp[0], Bq = xp[1], Cq = xp[2];
            const float xs[4][3] = {{A.x,  A.y,  A.z },
                                    {A.w,  Bq.x, Bq.y},
                                    {Bq.z, Bq.w, Cq.x},
                                    {Cq.y, Cq.z, Cq.w}};
#pragma unroll
            for (int g = 0; g < 16; ++g) {
                float4 w = sW1[g];           // 1 LDS read per 4 samples
#pragma unroll
                for (int m = 0; m < 4; ++m) {
                    float t0, t1, t2;
                    conv3_relu(xs[m][0], xs[m][1], xs[m][2],
                               w.x, w.y, w.z, w.w, t0, t1, t2);
                    upd(g, t0, t1, t2);
                }
            }
        } else {
            for (int m = 0; m < 4; ++m) {
                int s = s0 + m;
                if (s < B) accum1(x[3*s], x[3*s+1], x[3*s+2]);
            }
        }
    }

    // xor-tree: lane (L&31) ends holding total of slot (L&31)  [R3-proven]
    int lane = t & 63, wid = t >> 6;
#pragma unroll
    for (int i = 0; i < 32; ++i) cur[i] += __shfl_xor(cur[i], 32, 64);
#pragma unroll
    for (int half = 16; half >= 1; half >>= 1) {
#pragma unroll
        for (int i = 0; i < half; ++i) {
            bool up = (lane & half);
            float keep = up ? cur[i + half] : cur[i];
            float send = up ? cur[i] : cur[i + half];
            cur[i] = keep + __shfl_xor(send, half, 64);
        }
    }
    __shared__ float red[4][32];
    if (lane < 32) red[wid][lane] = cur[0];
    __syncthreads();
    if (t < 32)
        partials[blockIdx.x * 32 + t] = red[0][t] + red[1][t] + red[2][t] + red[3][t];
}

// ---------------------------------------------------------------------------
// Pass 2: conv2 per-channel stats, lane-pair split. fin1 redundantly in the
// prologue (R12-proven inside this kernel). Block 0 dumps sU/sC -> wU/wC.
// Last-finishing block runs fin2 (reduce p2 -> BN2 -> fw1sT/c1 -> global).
// partials[block*64 + v]: v<32 sum ch v, v>=32 sq ch v-32
// ---------------------------------------------------------------------------
__global__ __launch_bounds__(256) void k_stats2(const float* __restrict__ x,
                                                const float* __restrict__ w1,
                                                const float* __restrict__ b1,
                                                const float* __restrict__ p1,
                                                const float* __restrict__ g1,
                                                const float* __restrict__ bt1,
                                                const float* __restrict__ w2,
                                                const float* __restrict__ b2,
                                                const float* __restrict__ g2,
                                                const float* __restrict__ bt2,
                                                const float* __restrict__ fw1,
                                                const float* __restrict__ fb1,
                                                float* __restrict__ partials,
                                                float4* __restrict__ wU,
                                                float2* __restrict__ wC,
                                                float* __restrict__ fw1sT,
                                                float* __restrict__ c1,
                                                int* __restrict__ cnt,
                                                float Ninv, int nb1, int B)
{
    __shared__ float4 sW1[16];
    __shared__ float4 sU[32];   // ua,ub,uc,c0
    __shared__ float2 sC[32];   // c1,c2
    __shared__ float4 redbuf[256];
    __shared__ float tot[64];       // fin1 uses [0,32); fin2 uses [0,64)
    __shared__ float ssc[32], ssh[32];  // fin1 [0,16); fin2 [0,32)
    int t = threadIdx.x;

    // ---- redundant fin1: reduce p1 -> BN1 scale/shift -> folded conv2 wts
    {
        int v4 = t & 7, c = t >> 3;          // 8 float4 per p1 row
        float4 a = make_float4(0.f, 0.f, 0.f, 0.f);
        for (int b = c; b < nb1; b += 32) {
            float4 p = ((const float4*)p1)[b * 8 + v4];
            a.x += p.x; a.y += p.y; a.z += p.z; a.w += p.w;
        }
        redbuf[c * 8 + v4] = a;
    }
    if (t < 16) sW1[t] = make_float4(w1[3*t], w1[3*t+1], w1[3*t+2], b1[t]);
    __syncthreads();
    if (t < 8) {
        float4 a = make_float4(0.f, 0.f, 0.f, 0.f);
#pragma unroll
        for (int c = 0; c < 32; ++c) {
            float4 p = redbuf[c * 8 + t];
            a.x += p.x; a.y += p.y; a.z += p.z; a.w += p.w;
        }
        tot[4*t+0] = a.x; tot[4*t+1] = a.y; tot[4*t+2] = a.z; tot[4*t+3] = a.w;
    }
    __syncthreads();
    if (t < 16) {
        float mean = tot[t] * Ninv;
        float var  = fmaxf(tot[16 + t] * Ninv - mean * mean, 0.f);
        float rstd = rsqrtf(var + EPSV);
        float sc = g1[t] * rstd;
        ssc[t] = sc;
        ssh[t] = bt1[t] - mean * sc;
    }
    __syncthreads();
    if (t < 32) {
        int o = t, g = o >> 1;
        float sc = ssc[g], sh = ssh[g];
        float wv0 = w2[3*o], wv1 = w2[3*o+1], wv2 = w2[3*o+2];
        sU[o] = make_float4(wv0 * sc, wv1 * sc, wv2 * sc,
                            b2[o] + sh * (wv1 + wv2));          // bias pos0
        sC[o] = make_float2(b2[o] + sh * (wv0 + wv1 + wv2),     // bias pos1
                            b2[o] + sh * (wv0 + wv1));          // bias pos2
    }
    __syncthreads();
    // block 0 publishes the folded conv2 tables for k_final (kernel boundary
    // orders these stores vs k_final's loads)
    if (blockIdx.x == 0 && t < 32) { wU[t] = sU[t]; wC[t] = sC[t]; }

    const int p = t & 1;        // parity: which half of the channels
    const int gbase = 8 * p;    // conv groups [gbase, gbase+8)

    float cur[32];  // [0,16): sum ch 16p+i, [16,32): sq ch 16p+i
#pragma unroll
    for (int i = 0; i < 32; ++i) cur[i] = 0.f;

    auto updc = [&](int oc, float v0, float v1, float v2) {
        cur[oc]      += v0 + v1 + v2;
        cur[16 + oc]  = fmaf(v0, v0, fmaf(v1, v1, fmaf(v2, v2, cur[16 + oc])));
    };

    auto accum4 = [&](const float4& A, const float4& Bq, const float4& Cq) {
        const float xs[4][3] = {{A.x,  A.y,  A.z },
                                {A.w,  Bq.x, Bq.y},
                                {Bq.z, Bq.w, Cq.x},
                                {Cq.y, Cq.z, Cq.w}};
#pragma unroll
        for (int g = 0; g < 8; ++g) {
            float4 w = sW1[gbase + g];           // 1 read / 4 samples
            float r[4][3];
#pragma unroll
            for (int m = 0; m < 4; ++m)
                conv3_relu(xs[m][0], xs[m][1], xs[m][2],
                           w.x, w.y, w.z, w.w, r[m][0], r[m][1], r[m][2]);
#pragma unroll
            for (int jj = 0; jj < 2; ++jj) {
                int oc = 2 * g + jj;             // 0..15, compile-time const
                int oo = 16 * p + oc;            // LDS address only
                float4 u = sU[oo];               // 1 read / 4 samples
                float2 cc = sC[oo];
#pragma unroll
                for (int m = 0; m < 4; ++m) {
                    float v0 = fmaxf(fmaf(u.y, r[m][0], fmaf(u.z, r[m][1], u.w)), 0.f);
                    float v1 = fmaxf(fmaf(u.x, r[m][0], fmaf(u.y, r[m][1], fmaf(u.z, r[m][2], cc.x))), 0.f);
                    float v2 = fmaxf(fmaf(u.x, r[m][1], fmaf(u.y, r[m][2], cc.y)), 0.f);
                    updc(oc, v0, v1, v2);
                }
            }
        }
    };

    auto accum1 = [&](float x0, float x1, float x2) {   // tail only
#pragma unroll
        for (int g = 0; g < 8; ++g) {
            float4 w = sW1[gbase + g];
            float r0, r1, r2;
            conv3_relu(x0, x1, x2, w.x, w.y, w.z, w.w, r0, r1, r2);
#pragma unroll
            for (int jj = 0; jj < 2; ++jj) {
                int oc = 2 * g + jj;
                int oo = 16 * p + oc;
                float4 u = sU[oo];
                float2 cc = sC[oo];
                float v0 = fmaxf(fmaf(u.y, r0, fmaf(u.z, r1, u.w)), 0.f);
                float v1 = fmaxf(fmaf(u.x, r0, fmaf(u.y, r1, fmaf(u.z, r2, cc.x))), 0.f);
                float v2 = fmaxf(fmaf(u.x, r1, fmaf(u.y, r2, cc.y)), 0.f);
                updc(oc, v0, v1, v2);
            }
        }
    };

    int nchunk = (B + 3) >> 2;
    int gp     = (blockIdx.x * 256 + t) >> 1;       // global pair id
    int stride = (gridDim.x * 256) >> 1;
    for (int ch = gp; ch < nchunk; ch += stride) {
        int s0 = ch << 2;
        if (s0 + 4 <= B) {
            const float4* xp = (const float4*)(x + (size_t)s0 * 3);
            float4 A = xp[0], Bq = xp[1], Cq = xp[2];
            accum4(A, Bq, Cq);
        } else {
            for (int m = 0; m < 4; ++m) {
                int s = s0 + m;
                if (s < B) accum1(x[3*s], x[3*s+1], x[3*s+2]);
            }
        }
    }

    // parity-preserving xor-tree
    int lane = t & 63, wid = t >> 6;
#pragma unroll
    for (int half = 16; half >= 1; half >>= 1) {
        int d = half << 1;      // xor distance (keeps parity)
#pragma unroll
        for (int i = 0; i < half; ++i) {
            bool up = (lane & d);
            float keep = up ? cur[i + half] : cur[i];
            float send = up ? cur[i] : cur[i + half];
            cur[i] = keep + __shfl_xor(send, d, 64);
        }
    }
    __shared__ float red[4][64];
    {
        int idx = lane >> 1;
        int v = ((idx >> 4) << 5) + 16 * p + (idx & 15);
        red[wid][v] = cur[0];
    }
    __syncthreads();
    if (t < 64)
        partials[blockIdx.x * 64 + t] = red[0][t] + red[1][t] + red[2][t] + red[3][t];

    // ---- last-block fin2 epilogue (threadfence-reduction pattern) ----
    __shared__ int isLastS;
    __threadfence();            // publish this block's partials (all threads)
    __syncthreads();
    if (t == 0) {
        int prev = atomicAdd(cnt, 1);           // device-scope [m20]
        isLastS = (prev == (int)gridDim.x - 1);
    }
    __syncthreads();
    if (isLastS) {              // block-uniform branch -> __syncthreads legal
        __threadfence();        // acquire: all other blocks' partials visible
        int NBg = gridDim.x;
        {
            int v4 = t & 15, c = t >> 4;         // 16 float4 per p2 row
            float4 a = make_float4(0.f, 0.f, 0.f, 0.f);
            for (int b = c; b < NBg; b += 16) {
                float4 p = ((const float4*)partials)[b * 16 + v4];
                a.x += p.x; a.y += p.y; a.z += p.z; a.w += p.w;
            }
            redbuf[c * 16 + v4] = a;
        }
        __syncthreads();
        if (t < 16) {
            float4 a = make_float4(0.f, 0.f, 0.f, 0.f);
#pragma unroll
            for (int c = 0; c < 16; ++c) {
                float4 p = redbuf[c * 16 + t];
                a.x += p.x; a.y += p.y; a.z += p.z; a.w += p.w;
            }
            tot[4*t+0] = a.x; tot[4*t+1] = a.y; tot[4*t+2] = a.z; tot[4*t+3] = a.w;
        }
        __syncthreads();
        if (t < 32) {
            float mean = tot[t] * Ninv;
            float var  = fmaxf(tot[32 + t] * Ninv - mean * mean, 0.f);
            float rstd = rsqrtf(var + EPSV);
            float sc = g2[t] * rstd;
            ssc[t] = sc;
            ssh[t] = bt2[t] - mean * sc;
        }
        __syncthreads();
        for (int idx = t; idx < 512; idx += 256) {
            int o = idx >> 4, j = idx & 15;
            fw1sT[idx] = fw1[j * 32 + o] * ssc[o] * (1.0f / 3.0f);
        }
        if (t < 16) {
            float a = fb1[t];
#pragma unroll
            for (int c = 0; c < 32; ++c) a = fmaf(fw1[t * 32 + c], ssh[c], a);
            c1[t] = a;
        }
    }
}

// ---------------------------------------------------------------------------
// Pass 3: EXACT R11-proven kernel (40.6us): pure table loads into LDS, then
// the unroll-4 / plain-bounds main loop. No reductions in this kernel —
// R17 proved inlining them stalls this body 2.2x (schedule perturbation).
// ---------------------------------------------------------------------------
__global__ __launch_bounds__(256) void k_final(const float* __restrict__ x,
                                               const float* __restrict__ w1,
                                               const float* __restrict__ b1,
                                               const float4* __restrict__ wU,
                                               const float2* __restrict__ wC,
                                               const float* __restrict__ fw1sT,
                                               const float* __restrict__ c1,
                                               const float* __restrict__ fw2,
                                               const float* __restrict__ fb2,
                                               float* __restrict__ out,
                                               int B)
{
    __shared__ float4 sW1[16];   // conv1 w + b
    __shared__ float4 sU[32];    // conv2 w + bias(pos0)
    __shared__ float2 sC[32];    // bias(pos1), bias(pos2)
    __shared__ float4 sFT[128];  // sFT[o*4+k] = fw1sT[o*16+4k .. +3]
    __shared__ float2 sJ[16];    // (c1[j], fw2[j])
    __shared__ float  sb2;
    int t = threadIdx.x;
    if (t < 16) sW1[t] = make_float4(w1[3*t], w1[3*t+1], w1[3*t+2], b1[t]);
    else if (t >= 32 && t < 64) {
        int o = t - 32;
        sU[o] = wU[o];
        sC[o] = wC[o];
    } else if (t >= 64 && t < 192) {
        sFT[t - 64] = ((const float4*)fw1sT)[t - 64];
    } else if (t >= 192 && t < 208) {
        sJ[t - 192] = make_float2(c1[t - 192], fw2[t - 192]);
    } else if (t == 224) {
        sb2 = fb2[0];
    }
    __syncthreads();

    int nchunk = (B + 3) >> 2;
    for (int ch = blockIdx.x * 256 + t; ch < nchunk; ch += gridDim.x * 256) {
        int s0 = ch << 2;
        if (s0 + 4 <= B) {
            const float4* xp = (const float4*)(x + (size_t)s0 * 3);
            float4 A = xp[0], Bq = xp[1], Cq = xp[2];
            const float xs[4][3] = {{A.x,  A.y,  A.z },
                                    {A.w,  Bq.x, Bq.y},
                                    {Bq.z, Bq.w, Cq.x},
                                    {Cq.y, Cq.z, Cq.w}};

            float acc[4][16];
#pragma unroll
            for (int m = 0; m < 4; ++m)
#pragma unroll
                for (int j = 0; j < 16; ++j) acc[m][j] = 0.f;

#pragma unroll 4
            for (int g = 0; g < 16; ++g) {
                float4 w = sW1[g];               // 1 read / 4 samples
                float r[4][3];
#pragma unroll
                for (int m = 0; m < 4; ++m)
                    conv3_relu(xs[m][0], xs[m][1], xs[m][2],
                               w.x, w.y, w.z, w.w, r[m][0], r[m][1], r[m][2]);
#pragma unroll
                for (int jj = 0; jj < 2; ++jj) {
                    int o = 2 * g + jj;
                    float4 u = sU[o];            // 1 read / 4 samples
                    float2 cc = sC[o];
                    float so[4];
#pragma unroll
                    for (int m = 0; m < 4; ++m) {
                        float v0 = fmaxf(fmaf(u.y, r[m][0], fmaf(u.z, r[m][1], u.w)), 0.f);
                        float v1 = fmaxf(fmaf(u.x, r[m][0], fmaf(u.y, r[m][1], fmaf(u.z, r[m][2], cc.x))), 0.f);
                        float v2 = fmaxf(fmaf(u.x, r[m][1], fmaf(u.y, r[m][2], cc.y)), 0.f);
                        so[m] = v0 + v1 + v2;
                    }
#pragma unroll
                    for (int k = 0; k < 4; ++k) {
                        float4 f = sFT[o * 4 + k];   // 1 read / 4 samples
#pragma unroll
                        for (int m = 0; m < 4; ++m) {
                            acc[m][4*k+0] = fmaf(f.x, so[m], acc[m][4*k+0]);
                            acc[m][4*k+1] = fmaf(f.y, so[m], acc[m][4*k+1]);
                            acc[m][4*k+2] = fmaf(f.z, so[m], acc[m][4*k+2]);
                            acc[m][4*k+3] = fmaf(f.w, so[m], acc[m][4*k+3]);
                        }
                    }
                }
            }

            float res[4];
#pragma unroll
            for (int m = 0; m < 4; ++m) res[m] = sb2;
#pragma unroll
            for (int j = 0; j < 16; ++j) {
                float2 jw = sJ[j];               // 1 read / 4 samples
#pragma unroll
                for (int m = 0; m < 4; ++m)
                    res[m] = fmaf(jw.y, fmaxf(acc[m][j] + jw.x, 0.f), res[m]);
            }
            *(float4*)(out + s0) = make_float4(res[0], res[1], res[2], res[3]);
        } else {
            // tail: per-sample path
            for (int m = 0; m < 4; ++m) {
                int s = s0 + m;
                if (s >= B) break;
                float x0 = x[3*s], x1 = x[3*s+1], x2 = x[3*s+2];
                float acc1[16];
#pragma unroll
                for (int j = 0; j < 16; ++j) acc1[j] = 0.f;
#pragma unroll 4
                for (int g = 0; g < 16; ++g) {
                    float4 w = sW1[g];
                    float r0, r1, r2;
                    conv3_relu(x0, x1, x2, w.x, w.y, w.z, w.w, r0, r1, r2);
#pragma unroll
                    for (int jj = 0; jj < 2; ++jj) {
                        int o = 2 * g + jj;
                        float4 u = sU[o];
                        float2 cc = sC[o];
                        float v0 = fmaxf(fmaf(u.y, r0, fmaf(u.z, r1, u.w)), 0.f);
                        float v1 = fmaxf(fmaf(u.x, r0, fmaf(u.y, r1, fmaf(u.z, r2, cc.x))), 0.f);
                        float v2 = fmaxf(fmaf(u.x, r1, fmaf(u.y, r2, cc.y)), 0.f);
                        float so = v0 + v1 + v2;
#pragma unroll
                        for (int k = 0; k < 4; ++k) {
                            float4 f = sFT[o * 4 + k];
                            acc1[4*k+0] = fmaf(f.x, so, acc1[4*k+0]);
                            acc1[4*k+1] = fmaf(f.y, so, acc1[4*k+1]);
                            acc1[4*k+2] = fmaf(f.z, so, acc1[4*k+2]);
                            acc1[4*k+3] = fmaf(f.w, so, acc1[4*k+3]);
                        }
                    }
                }
                float r = sb2;
#pragma unroll
                for (int j = 0; j < 16; ++j) {
                    float2 jw = sJ[j];
                    r = fmaf(jw.y, fmaxf(acc1[j] + jw.x, 0.f), r);
                }
                out[s] = r;
            }
        }
    }
}

// ---------------------------------------------------------------------------
extern "C" void kernel_launch(void* const* d_in, const int* in_sizes, int n_in,
                              void* d_out, int out_size, void* d_ws, size_t ws_size,
                              hipStream_t stream)
{
    const float* x   = (const float*)d_in[0];
    const float* w1  = (const float*)d_in[1];
    const float* b1  = (const float*)d_in[2];
    const float* g1  = (const float*)d_in[3];
    const float* bt1 = (const float*)d_in[4];
    const float* w2  = (const float*)d_in[5];
    const float* b2  = (const float*)d_in[6];
    const float* g2  = (const float*)d_in[7];
    const float* bt2 = (const float*)d_in[8];
    const float* fw1 = (const float*)d_in[9];
    const float* fb1 = (const float*)d_in[10];
    const float* fw2 = (const float*)d_in[11];
    const float* fb2 = (const float*)d_in[12];

    int B = in_sizes[0] / 3;

    int nb1 = 512;    // stats1: 2 blocks/CU
    int nb2 = 512;    // stats2: 2 blocks/CU
    // ws floats: p1 nb1*32 | p2 nb2*64 | wU 128 | wC 64 | fw1sT 512 | c1 16 | cnt 1
    while ((size_t)(nb1 * 32 + nb2 * 64 + 128 + 64 + 512 + 16 + 1) * sizeof(float)
               > ws_size && nb1 > 1) {
        nb1 >>= 1; nb2 >>= 1;
    }

    float*  ws    = (float*)d_ws;
    float*  p1    = ws;                                  // nb1*32
    float*  p2    = ws + (size_t)nb1 * 32;               // nb2*64
    float4* wU    = (float4*)(p2 + (size_t)nb2 * 64);    // 32 float4 (16B-aligned)
    float2* wC    = (float2*)((float*)wU + 128);         // 32 float2
    float*  fw1sT = (float*)wC + 64;                     // 512
    float*  c1    = fw1sT + 512;                         // 16
    int*    cnt   = (int*)(c1 + 16);                     // 1 int

    float Ninv = 1.0f / (3.0f * (float)B);

    int nchunk = (B + 3) / 4;
    int gridF = (nchunk + 255) / 256;             // 4 samples/thread
    if (gridF > 2048) gridF = 2048;               // B=1M -> 1024 blocks

    // ws is poison-filled by the harness each iteration: zero the counter.
    hipMemsetAsync(cnt, 0, sizeof(int), stream);

    k_stats1<<<nb1, 256, 0, stream>>>(x, w1, b1, p1, B);
    k_stats2<<<nb2, 256, 0, stream>>>(x, w1, b1, p1, g1, bt1, w2, b2, g2, bt2,
                                      fw1, fb1, p2, wU, wC, fw1sT, c1, cnt,
                                      Ninv, nb1, B);
    k_final<<<gridF, 256, 0, stream>>>(x, w1, b1, wU, wC, fw1sT, c1,
                                       fw2, fb2, (float*)d_out, B);
}

// Round 11
// 154.730 us; speedup vs baseline: 1.2347x; 1.2347x over previous
//
#include <hip/hip_runtime.h>
#include <math.h>

#define EPSV 1e-5f

// conv1 (3-tap, zero-pad) + relu at the 3 positions of one sample
__device__ __forceinline__ void conv3_relu(float x0, float x1, float x2,
                                           float wa, float wb, float wc, float bb,
                                           float& t0, float& t1, float& t2)
{
    t0 = fmaxf(fmaf(wb, x0, fmaf(wc, x1, bb)), 0.f);
    t1 = fmaxf(fmaf(wa, x0, fmaf(wb, x1, fmaf(wc, x2, bb))), 0.f);
    t2 = fmaxf(fmaf(wa, x1, fmaf(wb, x2, bb)), 0.f);
}

// ---------------------------------------------------------------------------
// R20 = R19 resubmitted (R19 run died to container-infra failure, no data).
// Structure: 3 dispatches + 1 tiny memset. Cross-block stat combine is
// SHARDED float atomicAdd (8 shards by blockIdx&7; <=64 adds/address) —
// removes every nb-dependent reduction loop from every kernel:
//  - R18 lesson: fin2 epilogue co-compiled into k_stats2 dropped its VGPR to
//    52 and stalled the main loop (65us vs R12-proven <=40.6).
//  - R17 lesson: fin1+fin2 prologues co-compiled into k_final stalled the
//    unroll-4 body (89.6us vs 40.6). Rule: loop-bearing reductions must not
//    share a kernel with a proven hot loop.
// Now: stats kernels end with a 2-instruction atomic tail; k_stats2 prologue
// = "sum 8 shard floats -> BN1" (smaller than the R12-proven version);
// k_final prologue = "sum 8 shard floats -> BN2 -> fold fw1" (fixed-size,
// unrolled, ~2us) + the EXACT R11 main body (40.6us proven).
// fp32 atomic reorder noise ~ulp-level; threshold is 1.6e-2.
// ---------------------------------------------------------------------------

// ---------------------------------------------------------------------------
// Pass 1: per-channel sum/sumsq of relu(conv1(x)+b1), 16 ch.
// Group-outer / sample-inner. Tail: block-reduce in LDS then 32 sharded
// atomicAdds. accA[shard*32 + v]: v<16 sum, v>=16 sq.
// ---------------------------------------------------------------------------
__global__ __launch_bounds__(256) void k_stats1(const float* __restrict__ x,
                                                const float* __restrict__ w1,
                                                const float* __restrict__ b1,
                                                float* __restrict__ accA,
                                                int B)
{
    __shared__ float4 sW1[16];
    int t = threadIdx.x;
    if (t < 16) sW1[t] = make_float4(w1[3*t], w1[3*t+1], w1[3*t+2], b1[t]);
    __syncthreads();

    float cur[32];   // [0,16): sum, [16,32): sq
#pragma unroll
    for (int i = 0; i < 32; ++i) cur[i] = 0.f;

    auto upd = [&](int g, float t0, float t1, float t2) {
        cur[g]      += t0 + t1 + t2;
        cur[16 + g]  = fmaf(t0, t0, fmaf(t1, t1, fmaf(t2, t2, cur[16 + g])));
    };

    auto accum1 = [&](float x0, float x1, float x2) {   // tail only
#pragma unroll
        for (int g = 0; g < 16; ++g) {
            float4 w = sW1[g];
            float t0, t1, t2;
            conv3_relu(x0, x1, x2, w.x, w.y, w.z, w.w, t0, t1, t2);
            upd(g, t0, t1, t2);
        }
    };

    int nchunk = (B + 3) >> 2;
    for (int ch = blockIdx.x * 256 + t; ch < nchunk; ch += gridDim.x * 256) {
        int s0 = ch << 2;
        if (s0 + 4 <= B) {
            const float4* xp = (const float4*)(x + (size_t)s0 * 3);
            float4 A = xp[0], Bq = xp[1], Cq = xp[2];
            const float xs[4][3] = {{A.x,  A.y,  A.z },
                                    {A.w,  Bq.x, Bq.y},
                                    {Bq.z, Bq.w, Cq.x},
                                    {Cq.y, Cq.z, Cq.w}};
#pragma unroll
            for (int g = 0; g < 16; ++g) {
                float4 w = sW1[g];           // 1 LDS read per 4 samples
#pragma unroll
                for (int m = 0; m < 4; ++m) {
                    float t0, t1, t2;
                    conv3_relu(xs[m][0], xs[m][1], xs[m][2],
                               w.x, w.y, w.z, w.w, t0, t1, t2);
                    upd(g, t0, t1, t2);
                }
            }
        } else {
            for (int m = 0; m < 4; ++m) {
                int s = s0 + m;
                if (s < B) accum1(x[3*s], x[3*s+1], x[3*s+2]);
            }
        }
    }

    // xor-tree: lane (L&31) ends holding total of slot (L&31)  [R3-proven]
    int lane = t & 63, wid = t >> 6;
#pragma unroll
    for (int i = 0; i < 32; ++i) cur[i] += __shfl_xor(cur[i], 32, 64);
#pragma unroll
    for (int half = 16; half >= 1; half >>= 1) {
#pragma unroll
        for (int i = 0; i < half; ++i) {
            bool up = (lane & half);
            float keep = up ? cur[i + half] : cur[i];
            float send = up ? cur[i] : cur[i + half];
            cur[i] = keep + __shfl_xor(send, half, 64);
        }
    }
    __shared__ float red[4][32];
    if (lane < 32) red[wid][lane] = cur[0];
    __syncthreads();
    if (t < 32)
        atomicAdd(&accA[(blockIdx.x & 7) * 32 + t],
                  red[0][t] + red[1][t] + red[2][t] + red[3][t]);
}

// ---------------------------------------------------------------------------
// Pass 2: conv2 per-channel stats, lane-pair split (parity p=tid&1 owns conv
// groups [8p,8p+8)). Prologue: sum 8 shards -> BN1 -> sU/sC (loop-free;
// smaller than the R12-proven p1-reduce version). Block 0 publishes sU/sC to
// global wU/wC for k_final. Tail: 64 sharded atomicAdds. NO epilogue.
// accB[shard*64 + v]: v<32 sum ch v, v>=32 sq ch v-32.
// ---------------------------------------------------------------------------
__global__ __launch_bounds__(256) void k_stats2(const float* __restrict__ x,
                                                const float* __restrict__ w1,
                                                const float* __restrict__ b1,
                                                const float* __restrict__ accA,
                                                const float* __restrict__ g1,
                                                const float* __restrict__ bt1,
                                                const float* __restrict__ w2,
                                                const float* __restrict__ b2,
                                                float* __restrict__ accB,
                                                float4* __restrict__ wU,
                                                float2* __restrict__ wC,
                                                float Ninv, int B)
{
    __shared__ float4 sW1[16];
    __shared__ float4 sU[32];   // ua,ub,uc,c0
    __shared__ float2 sC[32];   // c1,c2
    __shared__ float tot[32];
    __shared__ float ssc[16], ssh[16];
    int t = threadIdx.x;

    // ---- BN1 consts from sharded totals (loop-free prologue)
    if (t < 16) sW1[t] = make_float4(w1[3*t], w1[3*t+1], w1[3*t+2], b1[t]);
    else if (t >= 32 && t < 64) {
        int v = t - 32;
        float s = 0.f;
#pragma unroll
        for (int sh = 0; sh < 8; ++sh) s += accA[sh * 32 + v];
        tot[v] = s;
    }
    __syncthreads();
    if (t < 16) {
        float mean = tot[t] * Ninv;
        float var  = fmaxf(tot[16 + t] * Ninv - mean * mean, 0.f);
        float rstd = rsqrtf(var + EPSV);
        float sc = g1[t] * rstd;
        ssc[t] = sc;
        ssh[t] = bt1[t] - mean * sc;
    }
    __syncthreads();
    if (t < 32) {
        int o = t, g = o >> 1;
        float sc = ssc[g], sh = ssh[g];
        float wv0 = w2[3*o], wv1 = w2[3*o+1], wv2 = w2[3*o+2];
        sU[o] = make_float4(wv0 * sc, wv1 * sc, wv2 * sc,
                            b2[o] + sh * (wv1 + wv2));          // bias pos0
        sC[o] = make_float2(b2[o] + sh * (wv0 + wv1 + wv2),     // bias pos1
                            b2[o] + sh * (wv0 + wv1));          // bias pos2
    }
    __syncthreads();
    // block 0 publishes folded conv2 tables for k_final (kernel boundary
    // orders these stores vs k_final's loads)
    if (blockIdx.x == 0 && t < 32) { wU[t] = sU[t]; wC[t] = sC[t]; }

    const int p = t & 1;        // parity: which half of the channels
    const int gbase = 8 * p;    // conv groups [gbase, gbase+8)

    float cur[32];  // [0,16): sum ch 16p+i, [16,32): sq ch 16p+i
#pragma unroll
    for (int i = 0; i < 32; ++i) cur[i] = 0.f;

    auto updc = [&](int oc, float v0, float v1, float v2) {
        cur[oc]      += v0 + v1 + v2;
        cur[16 + oc]  = fmaf(v0, v0, fmaf(v1, v1, fmaf(v2, v2, cur[16 + oc])));
    };

    auto accum4 = [&](const float4& A, const float4& Bq, const float4& Cq) {
        const float xs[4][3] = {{A.x,  A.y,  A.z },
                                {A.w,  Bq.x, Bq.y},
                                {Bq.z, Bq.w, Cq.x},
                                {Cq.y, Cq.z, Cq.w}};
#pragma unroll
        for (int g = 0; g < 8; ++g) {
            float4 w = sW1[gbase + g];           // 1 read / 4 samples
            float r[4][3];
#pragma unroll
            for (int m = 0; m < 4; ++m)
                conv3_relu(xs[m][0], xs[m][1], xs[m][2],
                           w.x, w.y, w.z, w.w, r[m][0], r[m][1], r[m][2]);
#pragma unroll
            for (int jj = 0; jj < 2; ++jj) {
                int oc = 2 * g + jj;             // 0..15, compile-time const
                int oo = 16 * p + oc;            // LDS address only
                float4 u = sU[oo];               // 1 read / 4 samples
                float2 cc = sC[oo];
#pragma unroll
                for (int m = 0; m < 4; ++m) {
                    float v0 = fmaxf(fmaf(u.y, r[m][0], fmaf(u.z, r[m][1], u.w)), 0.f);
                    float v1 = fmaxf(fmaf(u.x, r[m][0], fmaf(u.y, r[m][1], fmaf(u.z, r[m][2], cc.x))), 0.f);
                    float v2 = fmaxf(fmaf(u.x, r[m][1], fmaf(u.y, r[m][2], cc.y)), 0.f);
                    updc(oc, v0, v1, v2);
                }
            }
        }
    };

    auto accum1 = [&](float x0, float x1, float x2) {   // tail only
#pragma unroll
        for (int g = 0; g < 8; ++g) {
            float4 w = sW1[gbase + g];
            float r0, r1, r2;
            conv3_relu(x0, x1, x2, w.x, w.y, w.z, w.w, r0, r1, r2);
#pragma unroll
            for (int jj = 0; jj < 2; ++jj) {
                int oc = 2 * g + jj;
                int oo = 16 * p + oc;
                float4 u = sU[oo];
                float2 cc = sC[oo];
                float v0 = fmaxf(fmaf(u.y, r0, fmaf(u.z, r1, u.w)), 0.f);
                float v1 = fmaxf(fmaf(u.x, r0, fmaf(u.y, r1, fmaf(u.z, r2, cc.x))), 0.f);
                float v2 = fmaxf(fmaf(u.x, r1, fmaf(u.y, r2, cc.y)), 0.f);
                updc(oc, v0, v1, v2);
            }
        }
    };

    int nchunk = (B + 3) >> 2;
    int gp     = (blockIdx.x * 256 + t) >> 1;       // global pair id
    int stride = (gridDim.x * 256) >> 1;
    for (int ch = gp; ch < nchunk; ch += stride) {
        int s0 = ch << 2;
        if (s0 + 4 <= B) {
            const float4* xp = (const float4*)(x + (size_t)s0 * 3);
            float4 A = xp[0], Bq = xp[1], Cq = xp[2];
            accum4(A, Bq, Cq);
        } else {
            for (int m = 0; m < 4; ++m) {
                int s = s0 + m;
                if (s < B) accum1(x[3*s], x[3*s+1], x[3*s+2]);
            }
        }
    }

    // parity-preserving xor-tree: lane L ends with slot (L>>1) of its
    // parity's 32-slot vector.
    int lane = t & 63, wid = t >> 6;
#pragma unroll
    for (int half = 16; half >= 1; half >>= 1) {
        int d = half << 1;      // xor distance (keeps parity)
#pragma unroll
        for (int i = 0; i < half; ++i) {
            bool up = (lane & d);
            float keep = up ? cur[i + half] : cur[i];
            float send = up ? cur[i] : cur[i + half];
            cur[i] = keep + __shfl_xor(send, d, 64);
        }
    }
    __shared__ float red[4][64];
    {
        int idx = lane >> 1;
        int v = ((idx >> 4) << 5) + 16 * p + (idx & 15);
        red[wid][v] = cur[0];
    }
    __syncthreads();
    if (t < 64)
        atomicAdd(&accB[(blockIdx.x & 7) * 64 + t],
                  red[0][t] + red[1][t] + red[2][t] + red[3][t]);
}

// ---------------------------------------------------------------------------
// Pass 3: R11 main body (unroll 4, plain bounds, 40.6us proven) with a
// FIXED-SIZE loop-free-ish prologue: sum 8 shard floats -> BN2 -> fold fw1
// into sFT/sJ. No nb-dependent loops (the R17/R18 poison).
// ---------------------------------------------------------------------------
__global__ __launch_bounds__(256) void k_final(const float* __restrict__ x,
                                               const float* __restrict__ w1,
                                               const float* __restrict__ b1,
                                               const float4* __restrict__ wU,
                                               const float2* __restrict__ wC,
                                               const float* __restrict__ accB,
                                               const float* __restrict__ fw1,
                                               const float* __restrict__ fb1,
                                               const float* __restrict__ g2,
                                               const float* __restrict__ bt2,
                                               const float* __restrict__ fw2,
                                               const float* __restrict__ fb2,
                                               float* __restrict__ out,
                                               float Ninv, int B)
{
    __shared__ float4 sW1[16];   // conv1 w + b
    __shared__ float4 sU[32];    // conv2 w + bias(pos0)
    __shared__ float2 sC[32];    // bias(pos1), bias(pos2)
    __shared__ float4 sFT[128];  // sFT[o*4+k] = fold(fw1)[o*16+4k .. +3]
    __shared__ float2 sJ[16];    // (c1[j], fw2[j])
    __shared__ float  sb2;
    __shared__ float  totB[64];
    __shared__ float  s2c[32], s2h[32];
    int t = threadIdx.x;
    if (t < 16) sW1[t] = make_float4(w1[3*t], w1[3*t+1], w1[3*t+2], b1[t]);
    else if (t >= 32 && t < 64) {
        int o = t - 32;
        sU[o] = wU[o];
        sC[o] = wC[o];
    } else if (t >= 64 && t < 128) {
        int v = t - 64;
        float s = 0.f;
#pragma unroll
        for (int sh = 0; sh < 8; ++sh) s += accB[sh * 64 + v];
        totB[v] = s;
    } else if (t == 224) {
        sb2 = fb2[0];
    }
    __syncthreads();
    if (t < 32) {
        float mean = totB[t] * Ninv;
        float var  = fmaxf(totB[32 + t] * Ninv - mean * mean, 0.f);
        float sc = g2[t] * rsqrtf(var + EPSV);
        s2c[t] = sc;
        s2h[t] = bt2[t] - mean * sc;
    }
    __syncthreads();
    for (int idx = t; idx < 512; idx += 256) {
        int o = idx >> 4, j = idx & 15;
        ((float*)sFT)[o * 16 + j] = fw1[j * 32 + o] * s2c[o] * (1.0f / 3.0f);
    }
    if (t < 16) {
        float a = fb1[t];
#pragma unroll
        for (int c = 0; c < 32; ++c) a = fmaf(fw1[t * 32 + c], s2h[c], a);
        sJ[t] = make_float2(a, fw2[t]);
    }
    __syncthreads();

    int nchunk = (B + 3) >> 2;
    for (int ch = blockIdx.x * 256 + t; ch < nchunk; ch += gridDim.x * 256) {
        int s0 = ch << 2;
        if (s0 + 4 <= B) {
            const float4* xp = (const float4*)(x + (size_t)s0 * 3);
            float4 A = xp[0], Bq = xp[1], Cq = xp[2];
            const float xs[4][3] = {{A.x,  A.y,  A.z },
                                    {A.w,  Bq.x, Bq.y},
                                    {Bq.z, Bq.w, Cq.x},
                                    {Cq.y, Cq.z, Cq.w}};

            float acc[4][16];
#pragma unroll
            for (int m = 0; m < 4; ++m)
#pragma unroll
                for (int j = 0; j < 16; ++j) acc[m][j] = 0.f;

#pragma unroll 4
            for (int g = 0; g < 16; ++g) {
                float4 w = sW1[g];               // 1 read / 4 samples
                float r[4][3];
#pragma unroll
                for (int m = 0; m < 4; ++m)
                    conv3_relu(xs[m][0], xs[m][1], xs[m][2],
                               w.x, w.y, w.z, w.w, r[m][0], r[m][1], r[m][2]);
#pragma unroll
                for (int jj = 0; jj < 2; ++jj) {
                    int o = 2 * g + jj;
                    float4 u = sU[o];            // 1 read / 4 samples
                    float2 cc = sC[o];
                    float so[4];
#pragma unroll
                    for (int m = 0; m < 4; ++m) {
                        float v0 = fmaxf(fmaf(u.y, r[m][0], fmaf(u.z, r[m][1], u.w)), 0.f);
                        float v1 = fmaxf(fmaf(u.x, r[m][0], fmaf(u.y, r[m][1], fmaf(u.z, r[m][2], cc.x))), 0.f);
                        float v2 = fmaxf(fmaf(u.x, r[m][1], fmaf(u.y, r[m][2], cc.y)), 0.f);
                        so[m] = v0 + v1 + v2;
                    }
#pragma unroll
                    for (int k = 0; k < 4; ++k) {
                        float4 f = sFT[o * 4 + k];   // 1 read / 4 samples
#pragma unroll
                        for (int m = 0; m < 4; ++m) {
                            acc[m][4*k+0] = fmaf(f.x, so[m], acc[m][4*k+0]);
                            acc[m][4*k+1] = fmaf(f.y, so[m], acc[m][4*k+1]);
                            acc[m][4*k+2] = fmaf(f.z, so[m], acc[m][4*k+2]);
                            acc[m][4*k+3] = fmaf(f.w, so[m], acc[m][4*k+3]);
                        }
                    }
                }
            }

            float res[4];
#pragma unroll
            for (int m = 0; m < 4; ++m) res[m] = sb2;
#pragma unroll
            for (int j = 0; j < 16; ++j) {
                float2 jw = sJ[j];               // 1 read / 4 samples
#pragma unroll
                for (int m = 0; m < 4; ++m)
                    res[m] = fmaf(jw.y, fmaxf(acc[m][j] + jw.x, 0.f), res[m]);
            }
            *(float4*)(out + s0) = make_float4(res[0], res[1], res[2], res[3]);
        } else {
            // tail: per-sample path
            for (int m = 0; m < 4; ++m) {
                int s = s0 + m;
                if (s >= B) break;
                float x0 = x[3*s], x1 = x[3*s+1], x2 = x[3*s+2];
                float acc1[16];
#pragma unroll
                for (int j = 0; j < 16; ++j) acc1[j] = 0.f;
#pragma unroll 4
                for (int g = 0; g < 16; ++g) {
                    float4 w = sW1[g];
                    float r0, r1, r2;
                    conv3_relu(x0, x1, x2, w.x, w.y, w.z, w.w, r0, r1, r2);
#pragma unroll
                    for (int jj = 0; jj < 2; ++jj) {
                        int o = 2 * g + jj;
                        float4 u = sU[o];
                        float2 cc = sC[o];
                        float v0 = fmaxf(fmaf(u.y, r0, fmaf(u.z, r1, u.w)), 0.f);
                        float v1 = fmaxf(fmaf(u.x, r0, fmaf(u.y, r1, fmaf(u.z, r2, cc.x))), 0.f);
                        float v2 = fmaxf(fmaf(u.x, r1, fmaf(u.y, r2, cc.y)), 0.f);
                        float so = v0 + v1 + v2;
#pragma unroll
                        for (int k = 0; k < 4; ++k) {
                            float4 f = sFT[o * 4 + k];
                            acc1[4*k+0] = fmaf(f.x, so, acc1[4*k+0]);
                            acc1[4*k+1] = fmaf(f.y, so, acc1[4*k+1]);
                            acc1[4*k+2] = fmaf(f.z, so, acc1[4*k+2]);
                            acc1[4*k+3] = fmaf(f.w, so, acc1[4*k+3]);
                        }
                    }
                }
                float r = sb2;
#pragma unroll
                for (int j = 0; j < 16; ++j) {
                    float2 jw = sJ[j];
                    r = fmaf(jw.y, fmaxf(acc1[j] + jw.x, 0.f), r);
                }
                out[s] = r;
            }
        }
    }
}

// ---------------------------------------------------------------------------
extern "C" void kernel_launch(void* const* d_in, const int* in_sizes, int n_in,
                              void* d_out, int out_size, void* d_ws, size_t ws_size,
                              hipStream_t stream)
{
    const float* x   = (const float*)d_in[0];
    const float* w1  = (const float*)d_in[1];
    const float* b1  = (const float*)d_in[2];
    const float* g1  = (const float*)d_in[3];
    const float* bt1 = (const float*)d_in[4];
    const float* w2  = (const float*)d_in[5];
    const float* b2  = (const float*)d_in[6];
    const float* g2  = (const float*)d_in[7];
    const float* bt2 = (const float*)d_in[8];
    const float* fw1 = (const float*)d_in[9];
    const float* fb1 = (const float*)d_in[10];
    const float* fw2 = (const float*)d_in[11];
    const float* fb2 = (const float*)d_in[12];

    int B = in_sizes[0] / 3;

    // ws floats: accA 8*32=256 | accB 8*64=512 | wU 128 | wC 64  (=960 total)
    float*  ws   = (float*)d_ws;
    float*  accA = ws;                          // 256
    float*  accB = ws + 256;                    // 512
    float4* wU   = (float4*)(ws + 768);         // 32 float4 (16B aligned)
    float2* wC   = (float2*)(ws + 896);         // 32 float2

    float Ninv = 1.0f / (3.0f * (float)B);

    int nb1 = 512;    // stats1: 2 blocks/CU
    int nb2 = 512;    // stats2: 2 blocks/CU
    int nchunk = (B + 3) / 4;
    int gridF = (nchunk + 255) / 256;           // 4 samples/thread
    if (gridF > 2048) gridF = 2048;             // B=1M -> 1024 blocks

    // zero the sharded accumulators (ws is poison-filled each iteration)
    hipMemsetAsync(ws, 0, 768 * sizeof(float), stream);

    k_stats1<<<nb1, 256, 0, stream>>>(x, w1, b1, accA, B);
    k_stats2<<<nb2, 256, 0, stream>>>(x, w1, b1, accA, g1, bt1, w2, b2,
                                      accB, wU, wC, Ninv, B);
    k_final<<<gridF, 256, 0, stream>>>(x, w1, b1, wU, wC, accB, fw1, fb1,
                                       g2, bt2, fw2, fb2, (float*)d_out,
                                       Ninv, B);
}

// Round 12
// 149.776 us; speedup vs baseline: 1.2756x; 1.0331x over previous
//
#include <hip/hip_runtime.h>
#include <math.h>

#define EPSV 1e-5f

// conv1 (3-tap, zero-pad) + relu at the 3 positions of one sample
__device__ __forceinline__ void conv3_relu(float x0, float x1, float x2,
                                           float wa, float wb, float wc, float bb,
                                           float& t0, float& t1, float& t2)
{
    t0 = fmaxf(fmaf(wb, x0, fmaf(wc, x1, bb)), 0.f);
    t1 = fmaxf(fmaf(wa, x0, fmaf(wb, x1, fmaf(wc, x2, bb))), 0.f);
    t2 = fmaxf(fmaf(wa, x1, fmaf(wb, x2, bb)), 0.f);
}

// ---------------------------------------------------------------------------
// R21 = R20 (154.7us, best) + doubled stats grids. Sharded-atomic combine
// makes nb a free parameter (no consumer reduction scales with it):
//   nb1 = nb2 = 1024 (4 blocks/CU) -> stats work per thread halves.
//   Shards 8 -> 16 (blockIdx & 15) keeps contention at the proven
//   64 adds/address; consumer prologues stay fixed-size (16-iter sums).
// k_final byte-identical to R20 (43.6us measured; R11 body + fixed
// prologue). Proven rule (R17/R18 vs R20): nb-dependent reduction loops
// co-compiled with a hot loop stall it ~2x; fixed-size shard sums cost +3us.
// ---------------------------------------------------------------------------

#define NSHARD 16

// ---------------------------------------------------------------------------
// Pass 1: per-channel sum/sumsq of relu(conv1(x)+b1), 16 ch.
// Group-outer / sample-inner. Tail: block-reduce in LDS then 32 sharded
// atomicAdds. accA[shard*32 + v]: v<16 sum, v>=16 sq.
// ---------------------------------------------------------------------------
__global__ __launch_bounds__(256) void k_stats1(const float* __restrict__ x,
                                                const float* __restrict__ w1,
                                                const float* __restrict__ b1,
                                                float* __restrict__ accA,
                                                int B)
{
    __shared__ float4 sW1[16];
    int t = threadIdx.x;
    if (t < 16) sW1[t] = make_float4(w1[3*t], w1[3*t+1], w1[3*t+2], b1[t]);
    __syncthreads();

    float cur[32];   // [0,16): sum, [16,32): sq
#pragma unroll
    for (int i = 0; i < 32; ++i) cur[i] = 0.f;

    auto upd = [&](int g, float t0, float t1, float t2) {
        cur[g]      += t0 + t1 + t2;
        cur[16 + g]  = fmaf(t0, t0, fmaf(t1, t1, fmaf(t2, t2, cur[16 + g])));
    };

    auto accum1 = [&](float x0, float x1, float x2) {   // tail only
#pragma unroll
        for (int g = 0; g < 16; ++g) {
            float4 w = sW1[g];
            float t0, t1, t2;
            conv3_relu(x0, x1, x2, w.x, w.y, w.z, w.w, t0, t1, t2);
            upd(g, t0, t1, t2);
        }
    };

    int nchunk = (B + 3) >> 2;
    for (int ch = blockIdx.x * 256 + t; ch < nchunk; ch += gridDim.x * 256) {
        int s0 = ch << 2;
        if (s0 + 4 <= B) {
            const float4* xp = (const float4*)(x + (size_t)s0 * 3);
            float4 A = xp[0], Bq = xp[1], Cq = xp[2];
            const float xs[4][3] = {{A.x,  A.y,  A.z },
                                    {A.w,  Bq.x, Bq.y},
                                    {Bq.z, Bq.w, Cq.x},
                                    {Cq.y, Cq.z, Cq.w}};
#pragma unroll
            for (int g = 0; g < 16; ++g) {
                float4 w = sW1[g];           // 1 LDS read per 4 samples
#pragma unroll
                for (int m = 0; m < 4; ++m) {
                    float t0, t1, t2;
                    conv3_relu(xs[m][0], xs[m][1], xs[m][2],
                               w.x, w.y, w.z, w.w, t0, t1, t2);
                    upd(g, t0, t1, t2);
                }
            }
        } else {
            for (int m = 0; m < 4; ++m) {
                int s = s0 + m;
                if (s < B) accum1(x[3*s], x[3*s+1], x[3*s+2]);
            }
        }
    }

    // xor-tree: lane (L&31) ends holding total of slot (L&31)  [R3-proven]
    int lane = t & 63, wid = t >> 6;
#pragma unroll
    for (int i = 0; i < 32; ++i) cur[i] += __shfl_xor(cur[i], 32, 64);
#pragma unroll
    for (int half = 16; half >= 1; half >>= 1) {
#pragma unroll
        for (int i = 0; i < half; ++i) {
            bool up = (lane & half);
            float keep = up ? cur[i + half] : cur[i];
            float send = up ? cur[i] : cur[i + half];
            cur[i] = keep + __shfl_xor(send, half, 64);
        }
    }
    __shared__ float red[4][32];
    if (lane < 32) red[wid][lane] = cur[0];
    __syncthreads();
    if (t < 32)
        atomicAdd(&accA[(blockIdx.x & (NSHARD - 1)) * 32 + t],
                  red[0][t] + red[1][t] + red[2][t] + red[3][t]);
}

// ---------------------------------------------------------------------------
// Pass 2: conv2 per-channel stats, lane-pair split (parity p=tid&1 owns conv
// groups [8p,8p+8)). Prologue: sum 16 shards -> BN1 -> sU/sC (fixed-size).
// Block 0 publishes sU/sC to global wU/wC for k_final. Tail: 64 sharded
// atomicAdds. NO epilogue (R18 poison).
// accB[shard*64 + v]: v<32 sum ch v, v>=32 sq ch v-32.
// ---------------------------------------------------------------------------
__global__ __launch_bounds__(256) void k_stats2(const float* __restrict__ x,
                                                const float* __restrict__ w1,
                                                const float* __restrict__ b1,
                                                const float* __restrict__ accA,
                                                const float* __restrict__ g1,
                                                const float* __restrict__ bt1,
                                                const float* __restrict__ w2,
                                                const float* __restrict__ b2,
                                                float* __restrict__ accB,
                                                float4* __restrict__ wU,
                                                float2* __restrict__ wC,
                                                float Ninv, int B)
{
    __shared__ float4 sW1[16];
    __shared__ float4 sU[32];   // ua,ub,uc,c0
    __shared__ float2 sC[32];   // c1,c2
    __shared__ float tot[32];
    __shared__ float ssc[16], ssh[16];
    int t = threadIdx.x;

    // ---- BN1 consts from sharded totals (fixed-size prologue)
    if (t < 16) sW1[t] = make_float4(w1[3*t], w1[3*t+1], w1[3*t+2], b1[t]);
    else if (t >= 32 && t < 64) {
        int v = t - 32;
        float s = 0.f;
#pragma unroll
        for (int sh = 0; sh < NSHARD; ++sh) s += accA[sh * 32 + v];
        tot[v] = s;
    }
    __syncthreads();
    if (t < 16) {
        float mean = tot[t] * Ninv;
        float var  = fmaxf(tot[16 + t] * Ninv - mean * mean, 0.f);
        float rstd = rsqrtf(var + EPSV);
        float sc = g1[t] * rstd;
        ssc[t] = sc;
        ssh[t] = bt1[t] - mean * sc;
    }
    __syncthreads();
    if (t < 32) {
        int o = t, g = o >> 1;
        float sc = ssc[g], sh = ssh[g];
        float wv0 = w2[3*o], wv1 = w2[3*o+1], wv2 = w2[3*o+2];
        sU[o] = make_float4(wv0 * sc, wv1 * sc, wv2 * sc,
                            b2[o] + sh * (wv1 + wv2));          // bias pos0
        sC[o] = make_float2(b2[o] + sh * (wv0 + wv1 + wv2),     // bias pos1
                            b2[o] + sh * (wv0 + wv1));          // bias pos2
    }
    __syncthreads();
    // block 0 publishes folded conv2 tables for k_final (kernel boundary
    // orders these stores vs k_final's loads)
    if (blockIdx.x == 0 && t < 32) { wU[t] = sU[t]; wC[t] = sC[t]; }

    const int p = t & 1;        // parity: which half of the channels
    const int gbase = 8 * p;    // conv groups [gbase, gbase+8)

    float cur[32];  // [0,16): sum ch 16p+i, [16,32): sq ch 16p+i
#pragma unroll
    for (int i = 0; i < 32; ++i) cur[i] = 0.f;

    auto updc = [&](int oc, float v0, float v1, float v2) {
        cur[oc]      += v0 + v1 + v2;
        cur[16 + oc]  = fmaf(v0, v0, fmaf(v1, v1, fmaf(v2, v2, cur[16 + oc])));
    };

    auto accum4 = [&](const float4& A, const float4& Bq, const float4& Cq) {
        const float xs[4][3] = {{A.x,  A.y,  A.z },
                                {A.w,  Bq.x, Bq.y},
                                {Bq.z, Bq.w, Cq.x},
                                {Cq.y, Cq.z, Cq.w}};
#pragma unroll
        for (int g = 0; g < 8; ++g) {
            float4 w = sW1[gbase + g];           // 1 read / 4 samples
            float r[4][3];
#pragma unroll
            for (int m = 0; m < 4; ++m)
                conv3_relu(xs[m][0], xs[m][1], xs[m][2],
                           w.x, w.y, w.z, w.w, r[m][0], r[m][1], r[m][2]);
#pragma unroll
            for (int jj = 0; jj < 2; ++jj) {
                int oc = 2 * g + jj;             // 0..15, compile-time const
                int oo = 16 * p + oc;            // LDS address only
                float4 u = sU[oo];               // 1 read / 4 samples
                float2 cc = sC[oo];
#pragma unroll
                for (int m = 0; m < 4; ++m) {
                    float v0 = fmaxf(fmaf(u.y, r[m][0], fmaf(u.z, r[m][1], u.w)), 0.f);
                    float v1 = fmaxf(fmaf(u.x, r[m][0], fmaf(u.y, r[m][1], fmaf(u.z, r[m][2], cc.x))), 0.f);
                    float v2 = fmaxf(fmaf(u.x, r[m][1], fmaf(u.y, r[m][2], cc.y)), 0.f);
                    updc(oc, v0, v1, v2);
                }
            }
        }
    };

    auto accum1 = [&](float x0, float x1, float x2) {   // tail only
#pragma unroll
        for (int g = 0; g < 8; ++g) {
            float4 w = sW1[gbase + g];
            float r0, r1, r2;
            conv3_relu(x0, x1, x2, w.x, w.y, w.z, w.w, r0, r1, r2);
#pragma unroll
            for (int jj = 0; jj < 2; ++jj) {
                int oc = 2 * g + jj;
                int oo = 16 * p + oc;
                float4 u = sU[oo];
                float2 cc = sC[oo];
                float v0 = fmaxf(fmaf(u.y, r0, fmaf(u.z, r1, u.w)), 0.f);
                float v1 = fmaxf(fmaf(u.x, r0, fmaf(u.y, r1, fmaf(u.z, r2, cc.x))), 0.f);
                float v2 = fmaxf(fmaf(u.x, r1, fmaf(u.y, r2, cc.y)), 0.f);
                updc(oc, v0, v1, v2);
            }
        }
    };

    int nchunk = (B + 3) >> 2;
    int gp     = (blockIdx.x * 256 + t) >> 1;       // global pair id
    int stride = (gridDim.x * 256) >> 1;
    for (int ch = gp; ch < nchunk; ch += stride) {
        int s0 = ch << 2;
        if (s0 + 4 <= B) {
            const float4* xp = (const float4*)(x + (size_t)s0 * 3);
            float4 A = xp[0], Bq = xp[1], Cq = xp[2];
            accum4(A, Bq, Cq);
        } else {
            for (int m = 0; m < 4; ++m) {
                int s = s0 + m;
                if (s < B) accum1(x[3*s], x[3*s+1], x[3*s+2]);
            }
        }
    }

    // parity-preserving xor-tree: lane L ends with slot (L>>1) of its
    // parity's 32-slot vector.
    int lane = t & 63, wid = t >> 6;
#pragma unroll
    for (int half = 16; half >= 1; half >>= 1) {
        int d = half << 1;      // xor distance (keeps parity)
#pragma unroll
        for (int i = 0; i < half; ++i) {
            bool up = (lane & d);
            float keep = up ? cur[i + half] : cur[i];
            float send = up ? cur[i] : cur[i + half];
            cur[i] = keep + __shfl_xor(send, d, 64);
        }
    }
    __shared__ float red[4][64];
    {
        int idx = lane >> 1;
        int v = ((idx >> 4) << 5) + 16 * p + (idx & 15);
        red[wid][v] = cur[0];
    }
    __syncthreads();
    if (t < 64)
        atomicAdd(&accB[(blockIdx.x & (NSHARD - 1)) * 64 + t],
                  red[0][t] + red[1][t] + red[2][t] + red[3][t]);
}

// ---------------------------------------------------------------------------
// Pass 3: R11 main body (unroll 4, plain bounds, 40.6us proven) with a
// FIXED-SIZE prologue: sum 16 shard floats -> BN2 -> fold fw1 into sFT/sJ.
// No nb-dependent loops (the R17/R18 poison). Measured 43.6us in R20.
// ---------------------------------------------------------------------------
__global__ __launch_bounds__(256) void k_final(const float* __restrict__ x,
                                               const float* __restrict__ w1,
                                               const float* __restrict__ b1,
                                               const float4* __restrict__ wU,
                                               const float2* __restrict__ wC,
                                               const float* __restrict__ accB,
                                               const float* __restrict__ fw1,
                                               const float* __restrict__ fb1,
                                               const float* __restrict__ g2,
                                               const float* __restrict__ bt2,
                                               const float* __restrict__ fw2,
                                               const float* __restrict__ fb2,
                                               float* __restrict__ out,
                                               float Ninv, int B)
{
    __shared__ float4 sW1[16];   // conv1 w + b
    __shared__ float4 sU[32];    // conv2 w + bias(pos0)
    __shared__ float2 sC[32];    // bias(pos1), bias(pos2)
    __shared__ float4 sFT[128];  // sFT[o*4+k] = fold(fw1)[o*16+4k .. +3]
    __shared__ float2 sJ[16];    // (c1[j], fw2[j])
    __shared__ float  sb2;
    __shared__ float  totB[64];
    __shared__ float  s2c[32], s2h[32];
    int t = threadIdx.x;
    if (t < 16) sW1[t] = make_float4(w1[3*t], w1[3*t+1], w1[3*t+2], b1[t]);
    else if (t >= 32 && t < 64) {
        int o = t - 32;
        sU[o] = wU[o];
        sC[o] = wC[o];
    } else if (t >= 64 && t < 128) {
        int v = t - 64;
        float s = 0.f;
#pragma unroll
        for (int sh = 0; sh < NSHARD; ++sh) s += accB[sh * 64 + v];
        totB[v] = s;
    } else if (t == 224) {
        sb2 = fb2[0];
    }
    __syncthreads();
    if (t < 32) {
        float mean = totB[t] * Ninv;
        float var  = fmaxf(totB[32 + t] * Ninv - mean * mean, 0.f);
        float sc = g2[t] * rsqrtf(var + EPSV);
        s2c[t] = sc;
        s2h[t] = bt2[t] - mean * sc;
    }
    __syncthreads();
    for (int idx = t; idx < 512; idx += 256) {
        int o = idx >> 4, j = idx & 15;
        ((float*)sFT)[o * 16 + j] = fw1[j * 32 + o] * s2c[o] * (1.0f / 3.0f);
    }
    if (t < 16) {
        float a = fb1[t];
#pragma unroll
        for (int c = 0; c < 32; ++c) a = fmaf(fw1[t * 32 + c], s2h[c], a);
        sJ[t] = make_float2(a, fw2[t]);
    }
    __syncthreads();

    int nchunk = (B + 3) >> 2;
    for (int ch = blockIdx.x * 256 + t; ch < nchunk; ch += gridDim.x * 256) {
        int s0 = ch << 2;
        if (s0 + 4 <= B) {
            const float4* xp = (const float4*)(x + (size_t)s0 * 3);
            float4 A = xp[0], Bq = xp[1], Cq = xp[2];
            const float xs[4][3] = {{A.x,  A.y,  A.z },
                                    {A.w,  Bq.x, Bq.y},
                                    {Bq.z, Bq.w, Cq.x},
                                    {Cq.y, Cq.z, Cq.w}};

            float acc[4][16];
#pragma unroll
            for (int m = 0; m < 4; ++m)
#pragma unroll
                for (int j = 0; j < 16; ++j) acc[m][j] = 0.f;

#pragma unroll 4
            for (int g = 0; g < 16; ++g) {
                float4 w = sW1[g];               // 1 read / 4 samples
                float r[4][3];
#pragma unroll
                for (int m = 0; m < 4; ++m)
                    conv3_relu(xs[m][0], xs[m][1], xs[m][2],
                               w.x, w.y, w.z, w.w, r[m][0], r[m][1], r[m][2]);
#pragma unroll
                for (int jj = 0; jj < 2; ++jj) {
                    int o = 2 * g + jj;
                    float4 u = sU[o];            // 1 read / 4 samples
                    float2 cc = sC[o];
                    float so[4];
#pragma unroll
                    for (int m = 0; m < 4; ++m) {
                        float v0 = fmaxf(fmaf(u.y, r[m][0], fmaf(u.z, r[m][1], u.w)), 0.f);
                        float v1 = fmaxf(fmaf(u.x, r[m][0], fmaf(u.y, r[m][1], fmaf(u.z, r[m][2], cc.x))), 0.f);
                        float v2 = fmaxf(fmaf(u.x, r[m][1], fmaf(u.y, r[m][2], cc.y)), 0.f);
                        so[m] = v0 + v1 + v2;
                    }
#pragma unroll
                    for (int k = 0; k < 4; ++k) {
                        float4 f = sFT[o * 4 + k];   // 1 read / 4 samples
#pragma unroll
                        for (int m = 0; m < 4; ++m) {
                            acc[m][4*k+0] = fmaf(f.x, so[m], acc[m][4*k+0]);
                            acc[m][4*k+1] = fmaf(f.y, so[m], acc[m][4*k+1]);
                            acc[m][4*k+2] = fmaf(f.z, so[m], acc[m][4*k+2]);
                            acc[m][4*k+3] = fmaf(f.w, so[m], acc[m][4*k+3]);
                        }
                    }
                }
            }

            float res[4];
#pragma unroll
            for (int m = 0; m < 4; ++m) res[m] = sb2;
#pragma unroll
            for (int j = 0; j < 16; ++j) {
                float2 jw = sJ[j];               // 1 read / 4 samples
#pragma unroll
                for (int m = 0; m < 4; ++m)
                    res[m] = fmaf(jw.y, fmaxf(acc[m][j] + jw.x, 0.f), res[m]);
            }
            *(float4*)(out + s0) = make_float4(res[0], res[1], res[2], res[3]);
        } else {
            // tail: per-sample path
            for (int m = 0; m < 4; ++m) {
                int s = s0 + m;
                if (s >= B) break;
                float x0 = x[3*s], x1 = x[3*s+1], x2 = x[3*s+2];
                float acc1[16];
#pragma unroll
                for (int j = 0; j < 16; ++j) acc1[j] = 0.f;
#pragma unroll 4
                for (int g = 0; g < 16; ++g) {
                    float4 w = sW1[g];
                    float r0, r1, r2;
                    conv3_relu(x0, x1, x2, w.x, w.y, w.z, w.w, r0, r1, r2);
#pragma unroll
                    for (int jj = 0; jj < 2; ++jj) {
                        int o = 2 * g + jj;
                        float4 u = sU[o];
                        float2 cc = sC[o];
                        float v0 = fmaxf(fmaf(u.y, r0, fmaf(u.z, r1, u.w)), 0.f);
                        float v1 = fmaxf(fmaf(u.x, r0, fmaf(u.y, r1, fmaf(u.z, r2, cc.x))), 0.f);
                        float v2 = fmaxf(fmaf(u.x, r1, fmaf(u.y, r2, cc.y)), 0.f);
                        float so = v0 + v1 + v2;
#pragma unroll
                        for (int k = 0; k < 4; ++k) {
                            float4 f = sFT[o * 4 + k];
                            acc1[4*k+0] = fmaf(f.x, so, acc1[4*k+0]);
                            acc1[4*k+1] = fmaf(f.y, so, acc1[4*k+1]);
                            acc1[4*k+2] = fmaf(f.z, so, acc1[4*k+2]);
                            acc1[4*k+3] = fmaf(f.w, so, acc1[4*k+3]);
                        }
                    }
                }
                float r = sb2;
#pragma unroll
                for (int j = 0; j < 16; ++j) {
                    float2 jw = sJ[j];
                    r = fmaf(jw.y, fmaxf(acc1[j] + jw.x, 0.f), r);
                }
                out[s] = r;
            }
        }
    }
}

// ---------------------------------------------------------------------------
extern "C" void kernel_launch(void* const* d_in, const int* in_sizes, int n_in,
                              void* d_out, int out_size, void* d_ws, size_t ws_size,
                              hipStream_t stream)
{
    const float* x   = (const float*)d_in[0];
    const float* w1  = (const float*)d_in[1];
    const float* b1  = (const float*)d_in[2];
    const float* g1  = (const float*)d_in[3];
    const float* bt1 = (const float*)d_in[4];
    const float* w2  = (const float*)d_in[5];
    const float* b2  = (const float*)d_in[6];
    const float* g2  = (const float*)d_in[7];
    const float* bt2 = (const float*)d_in[8];
    const float* fw1 = (const float*)d_in[9];
    const float* fb1 = (const float*)d_in[10];
    const float* fw2 = (const float*)d_in[11];
    const float* fb2 = (const float*)d_in[12];

    int B = in_sizes[0] / 3;

    // ws floats: accA 16*32=512 | accB 16*64=1024 | wU 128 | wC 64 (=1728)
    float*  ws   = (float*)d_ws;
    float*  accA = ws;                          // 512
    float*  accB = ws + 512;                    // 1024
    float4* wU   = (float4*)(ws + 1536);        // 32 float4 (16B aligned)
    float2* wC   = (float2*)(ws + 1664);        // 32 float2

    float Ninv = 1.0f / (3.0f * (float)B);

    int nb1 = 1024;   // stats1: 4 blocks/CU (sharded atomics make nb free)
    int nb2 = 1024;   // stats2: 4 blocks/CU -> 2 chunk-iters/pair
    int nchunk = (B + 3) / 4;
    int gridF = (nchunk + 255) / 256;           // 4 samples/thread
    if (gridF > 2048) gridF = 2048;             // B=1M -> 1024 blocks

    // zero the sharded accumulators (ws is poison-filled each iteration)
    hipMemsetAsync(ws, 0, 1536 * sizeof(float), stream);

    k_stats1<<<nb1, 256, 0, stream>>>(x, w1, b1, accA, B);
    k_stats2<<<nb2, 256, 0, stream>>>(x, w1, b1, accA, g1, bt1, w2, b2,
                                      accB, wU, wC, Ninv, B);
    k_final<<<gridF, 256, 0, stream>>>(x, w1, b1, wU, wC, accB, fw1, fb1,
                                       g2, bt2, fw2, fb2, (float*)d_out,
                                       Ninv, B);
}

// Round 13
// 142.841 us; speedup vs baseline: 1.3375x; 1.0485x over previous
//
#include <hip/hip_runtime.h>
#include <math.h>

#define EPSV 1e-5f

// conv1 (3-tap, zero-pad) + relu at the 3 positions of one sample
__device__ __forceinline__ void conv3_relu(float x0, float x1, float x2,
                                           float wa, float wb, float wc, float bb,
                                           float& t0, float& t1, float& t2)
{
    t0 = fmaxf(fmaf(wb, x0, fmaf(wc, x1, bb)), 0.f);
    t1 = fmaxf(fmaf(wa, x0, fmaf(wb, x1, fmaf(wc, x2, bb))), 0.f);
    t2 = fmaxf(fmaf(wa, x1, fmaf(wb, x2, bb)), 0.f);
}

// ---------------------------------------------------------------------------
// R22 = R21 (149.8us best) + ONE change: __launch_bounds__(256,2) on the
// LEAN k_final. Rationale: k_final is latency-bound (VALUBusy 50%, 2 w/SIMD,
// VGPR 140; LDS+VALU floor ~15-20us vs 43.5 measured). R13's spill at the
// 128 cap is confounded — that kernel carried the nb-loop fin prologues
// (proven schedule poison, R17/R18). The lean kernel may fit 128 by
// tightening. Decision table pre-committed:
//   fits  (WRITE ~4.1MB, VGPR 128) -> 4 w/SIMD -> k_final ~28-34us
//   spill (WRITE >10MB)            -> revert to R21 next round
// ---------------------------------------------------------------------------

#define NSHARD 16

// ---------------------------------------------------------------------------
// Pass 1: per-channel sum/sumsq of relu(conv1(x)+b1), 16 ch.
// Group-outer / sample-inner. Tail: block-reduce in LDS then 32 sharded
// atomicAdds. accA[shard*32 + v]: v<16 sum, v>=16 sq.
// ---------------------------------------------------------------------------
__global__ __launch_bounds__(256) void k_stats1(const float* __restrict__ x,
                                                const float* __restrict__ w1,
                                                const float* __restrict__ b1,
                                                float* __restrict__ accA,
                                                int B)
{
    __shared__ float4 sW1[16];
    int t = threadIdx.x;
    if (t < 16) sW1[t] = make_float4(w1[3*t], w1[3*t+1], w1[3*t+2], b1[t]);
    __syncthreads();

    float cur[32];   // [0,16): sum, [16,32): sq
#pragma unroll
    for (int i = 0; i < 32; ++i) cur[i] = 0.f;

    auto upd = [&](int g, float t0, float t1, float t2) {
        cur[g]      += t0 + t1 + t2;
        cur[16 + g]  = fmaf(t0, t0, fmaf(t1, t1, fmaf(t2, t2, cur[16 + g])));
    };

    auto accum1 = [&](float x0, float x1, float x2) {   // tail only
#pragma unroll
        for (int g = 0; g < 16; ++g) {
            float4 w = sW1[g];
            float t0, t1, t2;
            conv3_relu(x0, x1, x2, w.x, w.y, w.z, w.w, t0, t1, t2);
            upd(g, t0, t1, t2);
        }
    };

    int nchunk = (B + 3) >> 2;
    for (int ch = blockIdx.x * 256 + t; ch < nchunk; ch += gridDim.x * 256) {
        int s0 = ch << 2;
        if (s0 + 4 <= B) {
            const float4* xp = (const float4*)(x + (size_t)s0 * 3);
            float4 A = xp[0], Bq = xp[1], Cq = xp[2];
            const float xs[4][3] = {{A.x,  A.y,  A.z },
                                    {A.w,  Bq.x, Bq.y},
                                    {Bq.z, Bq.w, Cq.x},
                                    {Cq.y, Cq.z, Cq.w}};
#pragma unroll
            for (int g = 0; g < 16; ++g) {
                float4 w = sW1[g];           // 1 LDS read per 4 samples
#pragma unroll
                for (int m = 0; m < 4; ++m) {
                    float t0, t1, t2;
                    conv3_relu(xs[m][0], xs[m][1], xs[m][2],
                               w.x, w.y, w.z, w.w, t0, t1, t2);
                    upd(g, t0, t1, t2);
                }
            }
        } else {
            for (int m = 0; m < 4; ++m) {
                int s = s0 + m;
                if (s < B) accum1(x[3*s], x[3*s+1], x[3*s+2]);
            }
        }
    }

    // xor-tree: lane (L&31) ends holding total of slot (L&31)  [R3-proven]
    int lane = t & 63, wid = t >> 6;
#pragma unroll
    for (int i = 0; i < 32; ++i) cur[i] += __shfl_xor(cur[i], 32, 64);
#pragma unroll
    for (int half = 16; half >= 1; half >>= 1) {
#pragma unroll
        for (int i = 0; i < half; ++i) {
            bool up = (lane & half);
            float keep = up ? cur[i + half] : cur[i];
            float send = up ? cur[i] : cur[i + half];
            cur[i] = keep + __shfl_xor(send, half, 64);
        }
    }
    __shared__ float red[4][32];
    if (lane < 32) red[wid][lane] = cur[0];
    __syncthreads();
    if (t < 32)
        atomicAdd(&accA[(blockIdx.x & (NSHARD - 1)) * 32 + t],
                  red[0][t] + red[1][t] + red[2][t] + red[3][t]);
}

// ---------------------------------------------------------------------------
// Pass 2: conv2 per-channel stats, lane-pair split (parity p=tid&1 owns conv
// groups [8p,8p+8)). Prologue: sum 16 shards -> BN1 -> sU/sC (fixed-size).
// Block 0 publishes sU/sC to global wU/wC for k_final. Tail: 64 sharded
// atomicAdds. NO epilogue (R18 poison).
// accB[shard*64 + v]: v<32 sum ch v, v>=32 sq ch v-32.
// ---------------------------------------------------------------------------
__global__ __launch_bounds__(256) void k_stats2(const float* __restrict__ x,
                                                const float* __restrict__ w1,
                                                const float* __restrict__ b1,
                                                const float* __restrict__ accA,
                                                const float* __restrict__ g1,
                                                const float* __restrict__ bt1,
                                                const float* __restrict__ w2,
                                                const float* __restrict__ b2,
                                                float* __restrict__ accB,
                                                float4* __restrict__ wU,
                                                float2* __restrict__ wC,
                                                float Ninv, int B)
{
    __shared__ float4 sW1[16];
    __shared__ float4 sU[32];   // ua,ub,uc,c0
    __shared__ float2 sC[32];   // c1,c2
    __shared__ float tot[32];
    __shared__ float ssc[16], ssh[16];
    int t = threadIdx.x;

    // ---- BN1 consts from sharded totals (fixed-size prologue)
    if (t < 16) sW1[t] = make_float4(w1[3*t], w1[3*t+1], w1[3*t+2], b1[t]);
    else if (t >= 32 && t < 64) {
        int v = t - 32;
        float s = 0.f;
#pragma unroll
        for (int sh = 0; sh < NSHARD; ++sh) s += accA[sh * 32 + v];
        tot[v] = s;
    }
    __syncthreads();
    if (t < 16) {
        float mean = tot[t] * Ninv;
        float var  = fmaxf(tot[16 + t] * Ninv - mean * mean, 0.f);
        float rstd = rsqrtf(var + EPSV);
        float sc = g1[t] * rstd;
        ssc[t] = sc;
        ssh[t] = bt1[t] - mean * sc;
    }
    __syncthreads();
    if (t < 32) {
        int o = t, g = o >> 1;
        float sc = ssc[g], sh = ssh[g];
        float wv0 = w2[3*o], wv1 = w2[3*o+1], wv2 = w2[3*o+2];
        sU[o] = make_float4(wv0 * sc, wv1 * sc, wv2 * sc,
                            b2[o] + sh * (wv1 + wv2));          // bias pos0
        sC[o] = make_float2(b2[o] + sh * (wv0 + wv1 + wv2),     // bias pos1
                            b2[o] + sh * (wv0 + wv1));          // bias pos2
    }
    __syncthreads();
    // block 0 publishes folded conv2 tables for k_final (kernel boundary
    // orders these stores vs k_final's loads)
    if (blockIdx.x == 0 && t < 32) { wU[t] = sU[t]; wC[t] = sC[t]; }

    const int p = t & 1;        // parity: which half of the channels
    const int gbase = 8 * p;    // conv groups [gbase, gbase+8)

    float cur[32];  // [0,16): sum ch 16p+i, [16,32): sq ch 16p+i
#pragma unroll
    for (int i = 0; i < 32; ++i) cur[i] = 0.f;

    auto updc = [&](int oc, float v0, float v1, float v2) {
        cur[oc]      += v0 + v1 + v2;
        cur[16 + oc]  = fmaf(v0, v0, fmaf(v1, v1, fmaf(v2, v2, cur[16 + oc])));
    };

    auto accum4 = [&](const float4& A, const float4& Bq, const float4& Cq) {
        const float xs[4][3] = {{A.x,  A.y,  A.z },
                                {A.w,  Bq.x, Bq.y},
                                {Bq.z, Bq.w, Cq.x},
                                {Cq.y, Cq.z, Cq.w}};
#pragma unroll
        for (int g = 0; g < 8; ++g) {
            float4 w = sW1[gbase + g];           // 1 read / 4 samples
            float r[4][3];
#pragma unroll
            for (int m = 0; m < 4; ++m)
                conv3_relu(xs[m][0], xs[m][1], xs[m][2],
                           w.x, w.y, w.z, w.w, r[m][0], r[m][1], r[m][2]);
#pragma unroll
            for (int jj = 0; jj < 2; ++jj) {
                int oc = 2 * g + jj;             // 0..15, compile-time const
                int oo = 16 * p + oc;            // LDS address only
                float4 u = sU[oo];               // 1 read / 4 samples
                float2 cc = sC[oo];
#pragma unroll
                for (int m = 0; m < 4; ++m) {
                    float v0 = fmaxf(fmaf(u.y, r[m][0], fmaf(u.z, r[m][1], u.w)), 0.f);
                    float v1 = fmaxf(fmaf(u.x, r[m][0], fmaf(u.y, r[m][1], fmaf(u.z, r[m][2], cc.x))), 0.f);
                    float v2 = fmaxf(fmaf(u.x, r[m][1], fmaf(u.y, r[m][2], cc.y)), 0.f);
                    updc(oc, v0, v1, v2);
                }
            }
        }
    };

    auto accum1 = [&](float x0, float x1, float x2) {   // tail only
#pragma unroll
        for (int g = 0; g < 8; ++g) {
            float4 w = sW1[gbase + g];
            float r0, r1, r2;
            conv3_relu(x0, x1, x2, w.x, w.y, w.z, w.w, r0, r1, r2);
#pragma unroll
            for (int jj = 0; jj < 2; ++jj) {
                int oc = 2 * g + jj;
                int oo = 16 * p + oc;
                float4 u = sU[oo];
                float2 cc = sC[oo];
                float v0 = fmaxf(fmaf(u.y, r0, fmaf(u.z, r1, u.w)), 0.f);
                float v1 = fmaxf(fmaf(u.x, r0, fmaf(u.y, r1, fmaf(u.z, r2, cc.x))), 0.f);
                float v2 = fmaxf(fmaf(u.x, r1, fmaf(u.y, r2, cc.y)), 0.f);
                updc(oc, v0, v1, v2);
            }
        }
    };

    int nchunk = (B + 3) >> 2;
    int gp     = (blockIdx.x * 256 + t) >> 1;       // global pair id
    int stride = (gridDim.x * 256) >> 1;
    for (int ch = gp; ch < nchunk; ch += stride) {
        int s0 = ch << 2;
        if (s0 + 4 <= B) {
            const float4* xp = (const float4*)(x + (size_t)s0 * 3);
            float4 A = xp[0], Bq = xp[1], Cq = xp[2];
            accum4(A, Bq, Cq);
        } else {
            for (int m = 0; m < 4; ++m) {
                int s = s0 + m;
                if (s < B) accum1(x[3*s], x[3*s+1], x[3*s+2]);
            }
        }
    }

    // parity-preserving xor-tree: lane L ends with slot (L>>1) of its
    // parity's 32-slot vector.
    int lane = t & 63, wid = t >> 6;
#pragma unroll
    for (int half = 16; half >= 1; half >>= 1) {
        int d = half << 1;      // xor distance (keeps parity)
#pragma unroll
        for (int i = 0; i < half; ++i) {
            bool up = (lane & d);
            float keep = up ? cur[i + half] : cur[i];
            float send = up ? cur[i] : cur[i + half];
            cur[i] = keep + __shfl_xor(send, d, 64);
        }
    }
    __shared__ float red[4][64];
    {
        int idx = lane >> 1;
        int v = ((idx >> 4) << 5) + 16 * p + (idx & 15);
        red[wid][v] = cur[0];
    }
    __syncthreads();
    if (t < 64)
        atomicAdd(&accB[(blockIdx.x & (NSHARD - 1)) * 64 + t],
                  red[0][t] + red[1][t] + red[2][t] + red[3][t]);
}

// ---------------------------------------------------------------------------
// Pass 3: R11 main body with fixed-size shard prologue (43.5us measured at
// VGPR 140, 2 w/SIMD). R22: __launch_bounds__(256,2) targets VGPR<=128 ->
// 4 w/SIMD. Latency-bound diagnosis: LDS+VALU floor ~15-20us, VALUBusy 50%.
// ---------------------------------------------------------------------------
__global__ __launch_bounds__(256, 2) void k_final(const float* __restrict__ x,
                                                  const float* __restrict__ w1,
                                                  const float* __restrict__ b1,
                                                  const float4* __restrict__ wU,
                                                  const float2* __restrict__ wC,
                                                  const float* __restrict__ accB,
                                                  const float* __restrict__ fw1,
                                                  const float* __restrict__ fb1,
                                                  const float* __restrict__ g2,
                                                  const float* __restrict__ bt2,
                                                  const float* __restrict__ fw2,
                                                  const float* __restrict__ fb2,
                                                  float* __restrict__ out,
                                                  float Ninv, int B)
{
    __shared__ float4 sW1[16];   // conv1 w + b
    __shared__ float4 sU[32];    // conv2 w + bias(pos0)
    __shared__ float2 sC[32];    // bias(pos1), bias(pos2)
    __shared__ float4 sFT[128];  // sFT[o*4+k] = fold(fw1)[o*16+4k .. +3]
    __shared__ float2 sJ[16];    // (c1[j], fw2[j])
    __shared__ float  sb2;
    __shared__ float  totB[64];
    __shared__ float  s2c[32], s2h[32];
    int t = threadIdx.x;
    if (t < 16) sW1[t] = make_float4(w1[3*t], w1[3*t+1], w1[3*t+2], b1[t]);
    else if (t >= 32 && t < 64) {
        int o = t - 32;
        sU[o] = wU[o];
        sC[o] = wC[o];
    } else if (t >= 64 && t < 128) {
        int v = t - 64;
        float s = 0.f;
#pragma unroll
        for (int sh = 0; sh < NSHARD; ++sh) s += accB[sh * 64 + v];
        totB[v] = s;
    } else if (t == 224) {
        sb2 = fb2[0];
    }
    __syncthreads();
    if (t < 32) {
        float mean = totB[t] * Ninv;
        float var  = fmaxf(totB[32 + t] * Ninv - mean * mean, 0.f);
        float sc = g2[t] * rsqrtf(var + EPSV);
        s2c[t] = sc;
        s2h[t] = bt2[t] - mean * sc;
    }
    __syncthreads();
    for (int idx = t; idx < 512; idx += 256) {
        int o = idx >> 4, j = idx & 15;
        ((float*)sFT)[o * 16 + j] = fw1[j * 32 + o] * s2c[o] * (1.0f / 3.0f);
    }
    if (t < 16) {
        float a = fb1[t];
#pragma unroll
        for (int c = 0; c < 32; ++c) a = fmaf(fw1[t * 32 + c], s2h[c], a);
        sJ[t] = make_float2(a, fw2[t]);
    }
    __syncthreads();

    int nchunk = (B + 3) >> 2;
    for (int ch = blockIdx.x * 256 + t; ch < nchunk; ch += gridDim.x * 256) {
        int s0 = ch << 2;
        if (s0 + 4 <= B) {
            const float4* xp = (const float4*)(x + (size_t)s0 * 3);
            float4 A = xp[0], Bq = xp[1], Cq = xp[2];
            const float xs[4][3] = {{A.x,  A.y,  A.z },
                                    {A.w,  Bq.x, Bq.y},
                                    {Bq.z, Bq.w, Cq.x},
                                    {Cq.y, Cq.z, Cq.w}};

            float acc[4][16];
#pragma unroll
            for (int m = 0; m < 4; ++m)
#pragma unroll
                for (int j = 0; j < 16; ++j) acc[m][j] = 0.f;

#pragma unroll 4
            for (int g = 0; g < 16; ++g) {
                float4 w = sW1[g];               // 1 read / 4 samples
                float r[4][3];
#pragma unroll
                for (int m = 0; m < 4; ++m)
                    conv3_relu(xs[m][0], xs[m][1], xs[m][2],
                               w.x, w.y, w.z, w.w, r[m][0], r[m][1], r[m][2]);
#pragma unroll
                for (int jj = 0; jj < 2; ++jj) {
                    int o = 2 * g + jj;
                    float4 u = sU[o];            // 1 read / 4 samples
                    float2 cc = sC[o];
                    float so[4];
#pragma unroll
                    for (int m = 0; m < 4; ++m) {
                        float v0 = fmaxf(fmaf(u.y, r[m][0], fmaf(u.z, r[m][1], u.w)), 0.f);
                        float v1 = fmaxf(fmaf(u.x, r[m][0], fmaf(u.y, r[m][1], fmaf(u.z, r[m][2], cc.x))), 0.f);
                        float v2 = fmaxf(fmaf(u.x, r[m][1], fmaf(u.y, r[m][2], cc.y)), 0.f);
                        so[m] = v0 + v1 + v2;
                    }
#pragma unroll
                    for (int k = 0; k < 4; ++k) {
                        float4 f = sFT[o * 4 + k];   // 1 read / 4 samples
#pragma unroll
                        for (int m = 0; m < 4; ++m) {
                            acc[m][4*k+0] = fmaf(f.x, so[m], acc[m][4*k+0]);
                            acc[m][4*k+1] = fmaf(f.y, so[m], acc[m][4*k+1]);
                            acc[m][4*k+2] = fmaf(f.z, so[m], acc[m][4*k+2]);
                            acc[m][4*k+3] = fmaf(f.w, so[m], acc[m][4*k+3]);
                        }
                    }
                }
            }

            float res[4];
#pragma unroll
            for (int m = 0; m < 4; ++m) res[m] = sb2;
#pragma unroll
            for (int j = 0; j < 16; ++j) {
                float2 jw = sJ[j];               // 1 read / 4 samples
#pragma unroll
                for (int m = 0; m < 4; ++m)
                    res[m] = fmaf(jw.y, fmaxf(acc[m][j] + jw.x, 0.f), res[m]);
            }
            *(float4*)(out + s0) = make_float4(res[0], res[1], res[2], res[3]);
        } else {
            // tail: per-sample path
            for (int m = 0; m < 4; ++m) {
                int s = s0 + m;
                if (s >= B) break;
                float x0 = x[3*s], x1 = x[3*s+1], x2 = x[3*s+2];
                float acc1[16];
#pragma unroll
                for (int j = 0; j < 16; ++j) acc1[j] = 0.f;
#pragma unroll 4
                for (int g = 0; g < 16; ++g) {
                    float4 w = sW1[g];
                    float r0, r1, r2;
                    conv3_relu(x0, x1, x2, w.x, w.y, w.z, w.w, r0, r1, r2);
#pragma unroll
                    for (int jj = 0; jj < 2; ++jj) {
                        int o = 2 * g + jj;
                        float4 u = sU[o];
                        float2 cc = sC[o];
                        float v0 = fmaxf(fmaf(u.y, r0, fmaf(u.z, r1, u.w)), 0.f);
                        float v1 = fmaxf(fmaf(u.x, r0, fmaf(u.y, r1, fmaf(u.z, r2, cc.x))), 0.f);
                        float v2 = fmaxf(fmaf(u.x, r1, fmaf(u.y, r2, cc.y)), 0.f);
                        float so = v0 + v1 + v2;
#pragma unroll
                        for (int k = 0; k < 4; ++k) {
                            float4 f = sFT[o * 4 + k];
                            acc1[4*k+0] = fmaf(f.x, so, acc1[4*k+0]);
                            acc1[4*k+1] = fmaf(f.y, so, acc1[4*k+1]);
                            acc1[4*k+2] = fmaf(f.z, so, acc1[4*k+2]);
                            acc1[4*k+3] = fmaf(f.w, so, acc1[4*k+3]);
                        }
                    }
                }
                float r = sb2;
#pragma unroll
                for (int j = 0; j < 16; ++j) {
                    float2 jw = sJ[j];
                    r = fmaf(jw.y, fmaxf(acc1[j] + jw.x, 0.f), r);
                }
                out[s] = r;
            }
        }
    }
}

// ---------------------------------------------------------------------------
extern "C" void kernel_launch(void* const* d_in, const int* in_sizes, int n_in,
                              void* d_out, int out_size, void* d_ws, size_t ws_size,
                              hipStream_t stream)
{
    const float* x   = (const float*)d_in[0];
    const float* w1  = (const float*)d_in[1];
    const float* b1  = (const float*)d_in[2];
    const float* g1  = (const float*)d_in[3];
    const float* bt1 = (const float*)d_in[4];
    const float* w2  = (const float*)d_in[5];
    const float* b2  = (const float*)d_in[6];
    const float* g2  = (const float*)d_in[7];
    const float* bt2 = (const float*)d_in[8];
    const float* fw1 = (const float*)d_in[9];
    const float* fb1 = (const float*)d_in[10];
    const float* fw2 = (const float*)d_in[11];
    const float* fb2 = (const float*)d_in[12];

    int B = in_sizes[0] / 3;

    // ws floats: accA 16*32=512 | accB 16*64=1024 | wU 128 | wC 64 (=1728)
    float*  ws   = (float*)d_ws;
    float*  accA = ws;                          // 512
    float*  accB = ws + 512;                    // 1024
    float4* wU   = (float4*)(ws + 1536);        // 32 float4 (16B aligned)
    float2* wC   = (float2*)(ws + 1664);        // 32 float2

    float Ninv = 1.0f / (3.0f * (float)B);

    int nb1 = 1024;   // stats1: 4 blocks/CU (sharded atomics make nb free)
    int nb2 = 1024;   // stats2: 4 blocks/CU -> 2 chunk-iters/pair
    int nchunk = (B + 3) / 4;
    int gridF = (nchunk + 255) / 256;           // 4 samples/thread
    if (gridF > 2048) gridF = 2048;             // B=1M -> 1024 blocks

    // zero the sharded accumulators (ws is poison-filled each iteration)
    hipMemsetAsync(ws, 0, 1536 * sizeof(float), stream);

    k_stats1<<<nb1, 256, 0, stream>>>(x, w1, b1, accA, B);
    k_stats2<<<nb2, 256, 0, stream>>>(x, w1, b1, accA, g1, bt1, w2, b2,
                                      accB, wU, wC, Ninv, B);
    k_final<<<gridF, 256, 0, stream>>>(x, w1, b1, wU, wC, accB, fw1, fb1,
                                       g2, bt2, fw2, fb2, (float*)d_out,
                                       Ninv, B);
}

// Round 14
// 142.317 us; speedup vs baseline: 1.3424x; 1.0037x over previous
//
#include <hip/hip_runtime.h>
#include <math.h>

#define EPSV 1e-5f

// conv1 (3-tap, zero-pad) + relu at the 3 positions of one sample
__device__ __forceinline__ void conv3_relu(float x0, float x1, float x2,
                                           float wa, float wb, float wc, float bb,
                                           float& t0, float& t1, float& t2)
{
    t0 = fmaxf(fmaf(wb, x0, fmaf(wc, x1, bb)), 0.f);
    t1 = fmaxf(fmaf(wa, x0, fmaf(wb, x1, fmaf(wc, x2, bb))), 0.f);
    t2 = fmaxf(fmaf(wa, x1, fmaf(wb, x2, bb)), 0.f);
}

// ---------------------------------------------------------------------------
// R23 = R22 (142.8us best) + ONE change: nb2 1024 -> 2048 (1 chunk/pair,
// the same saturation point stats1 already has), shards_B 16 -> 32 to hold
// atomic contention at the proven 64 adds/address. k_final byte-identical
// to R22 (fit at VGPR<=128 under (256,2); below the 43us top-5 cutoff).
// Occupancy ceiling notes: waves/SIMD steps at VGPR 64/128/256 [m69]; with
// >=64 live acc floats k_final can never reach the 8 w/SIMD tier -> 4 w/SIMD
// is its max; further gains would need VALU reduction (pk_fma), not waves.
// Accounting at R22: fill 43 (harness) + final ~35 + stats2 ~12 + stats1 ~3
// + memset ~1 + ~49 of graph-node gaps (~10/node).
// ---------------------------------------------------------------------------

#define NSHARD_A 16   // stats1: nb1=1024 blocks -> 64 adds/addr
#define NSHARD_B 32   // stats2: nb2=2048 blocks -> 64 adds/addr

// ---------------------------------------------------------------------------
// Pass 1: per-channel sum/sumsq of relu(conv1(x)+b1), 16 ch.
// Group-outer / sample-inner. Tail: block-reduce in LDS then 32 sharded
// atomicAdds. accA[shard*32 + v]: v<16 sum, v>=16 sq.
// ---------------------------------------------------------------------------
__global__ __launch_bounds__(256) void k_stats1(const float* __restrict__ x,
                                                const float* __restrict__ w1,
                                                const float* __restrict__ b1,
                                                float* __restrict__ accA,
                                                int B)
{
    __shared__ float4 sW1[16];
    int t = threadIdx.x;
    if (t < 16) sW1[t] = make_float4(w1[3*t], w1[3*t+1], w1[3*t+2], b1[t]);
    __syncthreads();

    float cur[32];   // [0,16): sum, [16,32): sq
#pragma unroll
    for (int i = 0; i < 32; ++i) cur[i] = 0.f;

    auto upd = [&](int g, float t0, float t1, float t2) {
        cur[g]      += t0 + t1 + t2;
        cur[16 + g]  = fmaf(t0, t0, fmaf(t1, t1, fmaf(t2, t2, cur[16 + g])));
    };

    auto accum1 = [&](float x0, float x1, float x2) {   // tail only
#pragma unroll
        for (int g = 0; g < 16; ++g) {
            float4 w = sW1[g];
            float t0, t1, t2;
            conv3_relu(x0, x1, x2, w.x, w.y, w.z, w.w, t0, t1, t2);
            upd(g, t0, t1, t2);
        }
    };

    int nchunk = (B + 3) >> 2;
    for (int ch = blockIdx.x * 256 + t; ch < nchunk; ch += gridDim.x * 256) {
        int s0 = ch << 2;
        if (s0 + 4 <= B) {
            const float4* xp = (const float4*)(x + (size_t)s0 * 3);
            float4 A = xp[0], Bq = xp[1], Cq = xp[2];
            const float xs[4][3] = {{A.x,  A.y,  A.z },
                                    {A.w,  Bq.x, Bq.y},
                                    {Bq.z, Bq.w, Cq.x},
                                    {Cq.y, Cq.z, Cq.w}};
#pragma unroll
            for (int g = 0; g < 16; ++g) {
                float4 w = sW1[g];           // 1 LDS read per 4 samples
#pragma unroll
                for (int m = 0; m < 4; ++m) {
                    float t0, t1, t2;
                    conv3_relu(xs[m][0], xs[m][1], xs[m][2],
                               w.x, w.y, w.z, w.w, t0, t1, t2);
                    upd(g, t0, t1, t2);
                }
            }
        } else {
            for (int m = 0; m < 4; ++m) {
                int s = s0 + m;
                if (s < B) accum1(x[3*s], x[3*s+1], x[3*s+2]);
            }
        }
    }

    // xor-tree: lane (L&31) ends holding total of slot (L&31)  [R3-proven]
    int lane = t & 63, wid = t >> 6;
#pragma unroll
    for (int i = 0; i < 32; ++i) cur[i] += __shfl_xor(cur[i], 32, 64);
#pragma unroll
    for (int half = 16; half >= 1; half >>= 1) {
#pragma unroll
        for (int i = 0; i < half; ++i) {
            bool up = (lane & half);
            float keep = up ? cur[i + half] : cur[i];
            float send = up ? cur[i] : cur[i + half];
            cur[i] = keep + __shfl_xor(send, half, 64);
        }
    }
    __shared__ float red[4][32];
    if (lane < 32) red[wid][lane] = cur[0];
    __syncthreads();
    if (t < 32)
        atomicAdd(&accA[(blockIdx.x & (NSHARD_A - 1)) * 32 + t],
                  red[0][t] + red[1][t] + red[2][t] + red[3][t]);
}

// ---------------------------------------------------------------------------
// Pass 2: conv2 per-channel stats, lane-pair split (parity p=tid&1 owns conv
// groups [8p,8p+8)). Prologue: sum 16 shards -> BN1 -> sU/sC (fixed-size).
// Block 0 publishes sU/sC to global wU/wC for k_final. Tail: 64 sharded
// atomicAdds into 32 shards. NO epilogue (R18 poison).
// accB[shard*64 + v]: v<32 sum ch v, v>=32 sq ch v-32.
// ---------------------------------------------------------------------------
__global__ __launch_bounds__(256) void k_stats2(const float* __restrict__ x,
                                                const float* __restrict__ w1,
                                                const float* __restrict__ b1,
                                                const float* __restrict__ accA,
                                                const float* __restrict__ g1,
                                                const float* __restrict__ bt1,
                                                const float* __restrict__ w2,
                                                const float* __restrict__ b2,
                                                float* __restrict__ accB,
                                                float4* __restrict__ wU,
                                                float2* __restrict__ wC,
                                                float Ninv, int B)
{
    __shared__ float4 sW1[16];
    __shared__ float4 sU[32];   // ua,ub,uc,c0
    __shared__ float2 sC[32];   // c1,c2
    __shared__ float tot[32];
    __shared__ float ssc[16], ssh[16];
    int t = threadIdx.x;

    // ---- BN1 consts from sharded totals (fixed-size prologue)
    if (t < 16) sW1[t] = make_float4(w1[3*t], w1[3*t+1], w1[3*t+2], b1[t]);
    else if (t >= 32 && t < 64) {
        int v = t - 32;
        float s = 0.f;
#pragma unroll
        for (int sh = 0; sh < NSHARD_A; ++sh) s += accA[sh * 32 + v];
        tot[v] = s;
    }
    __syncthreads();
    if (t < 16) {
        float mean = tot[t] * Ninv;
        float var  = fmaxf(tot[16 + t] * Ninv - mean * mean, 0.f);
        float rstd = rsqrtf(var + EPSV);
        float sc = g1[t] * rstd;
        ssc[t] = sc;
        ssh[t] = bt1[t] - mean * sc;
    }
    __syncthreads();
    if (t < 32) {
        int o = t, g = o >> 1;
        float sc = ssc[g], sh = ssh[g];
        float wv0 = w2[3*o], wv1 = w2[3*o+1], wv2 = w2[3*o+2];
        sU[o] = make_float4(wv0 * sc, wv1 * sc, wv2 * sc,
                            b2[o] + sh * (wv1 + wv2));          // bias pos0
        sC[o] = make_float2(b2[o] + sh * (wv0 + wv1 + wv2),     // bias pos1
                            b2[o] + sh * (wv0 + wv1));          // bias pos2
    }
    __syncthreads();
    // block 0 publishes folded conv2 tables for k_final (kernel boundary
    // orders these stores vs k_final's loads)
    if (blockIdx.x == 0 && t < 32) { wU[t] = sU[t]; wC[t] = sC[t]; }

    const int p = t & 1;        // parity: which half of the channels
    const int gbase = 8 * p;    // conv groups [gbase, gbase+8)

    float cur[32];  // [0,16): sum ch 16p+i, [16,32): sq ch 16p+i
#pragma unroll
    for (int i = 0; i < 32; ++i) cur[i] = 0.f;

    auto updc = [&](int oc, float v0, float v1, float v2) {
        cur[oc]      += v0 + v1 + v2;
        cur[16 + oc]  = fmaf(v0, v0, fmaf(v1, v1, fmaf(v2, v2, cur[16 + oc])));
    };

    auto accum4 = [&](const float4& A, const float4& Bq, const float4& Cq) {
        const float xs[4][3] = {{A.x,  A.y,  A.z },
                                {A.w,  Bq.x, Bq.y},
                                {Bq.z, Bq.w, Cq.x},
                                {Cq.y, Cq.z, Cq.w}};
#pragma unroll
        for (int g = 0; g < 8; ++g) {
            float4 w = sW1[gbase + g];           // 1 read / 4 samples
            float r[4][3];
#pragma unroll
            for (int m = 0; m < 4; ++m)
                conv3_relu(xs[m][0], xs[m][1], xs[m][2],
                           w.x, w.y, w.z, w.w, r[m][0], r[m][1], r[m][2]);
#pragma unroll
            for (int jj = 0; jj < 2; ++jj) {
                int oc = 2 * g + jj;             // 0..15, compile-time const
                int oo = 16 * p + oc;            // LDS address only
                float4 u = sU[oo];               // 1 read / 4 samples
                float2 cc = sC[oo];
#pragma unroll
                for (int m = 0; m < 4; ++m) {
                    float v0 = fmaxf(fmaf(u.y, r[m][0], fmaf(u.z, r[m][1], u.w)), 0.f);
                    float v1 = fmaxf(fmaf(u.x, r[m][0], fmaf(u.y, r[m][1], fmaf(u.z, r[m][2], cc.x))), 0.f);
                    float v2 = fmaxf(fmaf(u.x, r[m][1], fmaf(u.y, r[m][2], cc.y)), 0.f);
                    updc(oc, v0, v1, v2);
                }
            }
        }
    };

    auto accum1 = [&](float x0, float x1, float x2) {   // tail only
#pragma unroll
        for (int g = 0; g < 8; ++g) {
            float4 w = sW1[gbase + g];
            float r0, r1, r2;
            conv3_relu(x0, x1, x2, w.x, w.y, w.z, w.w, r0, r1, r2);
#pragma unroll
            for (int jj = 0; jj < 2; ++jj) {
                int oc = 2 * g + jj;
                int oo = 16 * p + oc;
                float4 u = sU[oo];
                float2 cc = sC[oo];
                float v0 = fmaxf(fmaf(u.y, r0, fmaf(u.z, r1, u.w)), 0.f);
                float v1 = fmaxf(fmaf(u.x, r0, fmaf(u.y, r1, fmaf(u.z, r2, cc.x))), 0.f);
                float v2 = fmaxf(fmaf(u.x, r1, fmaf(u.y, r2, cc.y)), 0.f);
                updc(oc, v0, v1, v2);
            }
        }
    };

    int nchunk = (B + 3) >> 2;
    int gp     = (blockIdx.x * 256 + t) >> 1;       // global pair id
    int stride = (gridDim.x * 256) >> 1;
    for (int ch = gp; ch < nchunk; ch += stride) {
        int s0 = ch << 2;
        if (s0 + 4 <= B) {
            const float4* xp = (const float4*)(x + (size_t)s0 * 3);
            float4 A = xp[0], Bq = xp[1], Cq = xp[2];
            accum4(A, Bq, Cq);
        } else {
            for (int m = 0; m < 4; ++m) {
                int s = s0 + m;
                if (s < B) accum1(x[3*s], x[3*s+1], x[3*s+2]);
            }
        }
    }

    // parity-preserving xor-tree: lane L ends with slot (L>>1) of its
    // parity's 32-slot vector.
    int lane = t & 63, wid = t >> 6;
#pragma unroll
    for (int half = 16; half >= 1; half >>= 1) {
        int d = half << 1;      // xor distance (keeps parity)
#pragma unroll
        for (int i = 0; i < half; ++i) {
            bool up = (lane & d);
            float keep = up ? cur[i + half] : cur[i];
            float send = up ? cur[i] : cur[i + half];
            cur[i] = keep + __shfl_xor(send, d, 64);
        }
    }
    __shared__ float red[4][64];
    {
        int idx = lane >> 1;
        int v = ((idx >> 4) << 5) + 16 * p + (idx & 15);
        red[wid][v] = cur[0];
    }
    __syncthreads();
    if (t < 64)
        atomicAdd(&accB[(blockIdx.x & (NSHARD_B - 1)) * 64 + t],
                  red[0][t] + red[1][t] + red[2][t] + red[3][t]);
}

// ---------------------------------------------------------------------------
// Pass 3: R11 main body with fixed-size shard prologue, __launch_bounds__
// (256,2) (R22-proven: fits at VGPR<=128, no spill, <43us). Byte-identical
// to R22 except NSHARD_B=32 in the prologue sum (still fixed-size).
// ---------------------------------------------------------------------------
__global__ __launch_bounds__(256, 2) void k_final(const float* __restrict__ x,
                                                  const float* __restrict__ w1,
                                                  const float* __restrict__ b1,
                                                  const float4* __restrict__ wU,
                                                  const float2* __restrict__ wC,
                                                  const float* __restrict__ accB,
                                                  const float* __restrict__ fw1,
                                                  const float* __restrict__ fb1,
                                                  const float* __restrict__ g2,
                                                  const float* __restrict__ bt2,
                                                  const float* __restrict__ fw2,
                                                  const float* __restrict__ fb2,
                                                  float* __restrict__ out,
                                                  float Ninv, int B)
{
    __shared__ float4 sW1[16];   // conv1 w + b
    __shared__ float4 sU[32];    // conv2 w + bias(pos0)
    __shared__ float2 sC[32];    // bias(pos1), bias(pos2)
    __shared__ float4 sFT[128];  // sFT[o*4+k] = fold(fw1)[o*16+4k .. +3]
    __shared__ float2 sJ[16];    // (c1[j], fw2[j])
    __shared__ float  sb2;
    __shared__ float  totB[64];
    __shared__ float  s2c[32], s2h[32];
    int t = threadIdx.x;
    if (t < 16) sW1[t] = make_float4(w1[3*t], w1[3*t+1], w1[3*t+2], b1[t]);
    else if (t >= 32 && t < 64) {
        int o = t - 32;
        sU[o] = wU[o];
        sC[o] = wC[o];
    } else if (t >= 64 && t < 128) {
        int v = t - 64;
        float s = 0.f;
#pragma unroll
        for (int sh = 0; sh < NSHARD_B; ++sh) s += accB[sh * 64 + v];
        totB[v] = s;
    } else if (t == 224) {
        sb2 = fb2[0];
    }
    __syncthreads();
    if (t < 32) {
        float mean = totB[t] * Ninv;
        float var  = fmaxf(totB[32 + t] * Ninv - mean * mean, 0.f);
        float sc = g2[t] * rsqrtf(var + EPSV);
        s2c[t] = sc;
        s2h[t] = bt2[t] - mean * sc;
    }
    __syncthreads();
    for (int idx = t; idx < 512; idx += 256) {
        int o = idx >> 4, j = idx & 15;
        ((float*)sFT)[o * 16 + j] = fw1[j * 32 + o] * s2c[o] * (1.0f / 3.0f);
    }
    if (t < 16) {
        float a = fb1[t];
#pragma unroll
        for (int c = 0; c < 32; ++c) a = fmaf(fw1[t * 32 + c], s2h[c], a);
        sJ[t] = make_float2(a, fw2[t]);
    }
    __syncthreads();

    int nchunk = (B + 3) >> 2;
    for (int ch = blockIdx.x * 256 + t; ch < nchunk; ch += gridDim.x * 256) {
        int s0 = ch << 2;
        if (s0 + 4 <= B) {
            const float4* xp = (const float4*)(x + (size_t)s0 * 3);
            float4 A = xp[0], Bq = xp[1], Cq = xp[2];
            const float xs[4][3] = {{A.x,  A.y,  A.z },
                                    {A.w,  Bq.x, Bq.y},
                                    {Bq.z, Bq.w, Cq.x},
                                    {Cq.y, Cq.z, Cq.w}};

            float acc[4][16];
#pragma unroll
            for (int m = 0; m < 4; ++m)
#pragma unroll
                for (int j = 0; j < 16; ++j) acc[m][j] = 0.f;

#pragma unroll 4
            for (int g = 0; g < 16; ++g) {
                float4 w = sW1[g];               // 1 read / 4 samples
                float r[4][3];
#pragma unroll
                for (int m = 0; m < 4; ++m)
                    conv3_relu(xs[m][0], xs[m][1], xs[m][2],
                               w.x, w.y, w.z, w.w, r[m][0], r[m][1], r[m][2]);
#pragma unroll
                for (int jj = 0; jj < 2; ++jj) {
                    int o = 2 * g + jj;
                    float4 u = sU[o];            // 1 read / 4 samples
                    float2 cc = sC[o];
                    float so[4];
#pragma unroll
                    for (int m = 0; m < 4; ++m) {
                        float v0 = fmaxf(fmaf(u.y, r[m][0], fmaf(u.z, r[m][1], u.w)), 0.f);
                        float v1 = fmaxf(fmaf(u.x, r[m][0], fmaf(u.y, r[m][1], fmaf(u.z, r[m][2], cc.x))), 0.f);
                        float v2 = fmaxf(fmaf(u.x, r[m][1], fmaf(u.y, r[m][2], cc.y)), 0.f);
                        so[m] = v0 + v1 + v2;
                    }
#pragma unroll
                    for (int k = 0; k < 4; ++k) {
                        float4 f = sFT[o * 4 + k];   // 1 read / 4 samples
#pragma unroll
                        for (int m = 0; m < 4; ++m) {
                            acc[m][4*k+0] = fmaf(f.x, so[m], acc[m][4*k+0]);
                            acc[m][4*k+1] = fmaf(f.y, so[m], acc[m][4*k+1]);
                            acc[m][4*k+2] = fmaf(f.z, so[m], acc[m][4*k+2]);
                            acc[m][4*k+3] = fmaf(f.w, so[m], acc[m][4*k+3]);
                        }
                    }
                }
            }

            float res[4];
#pragma unroll
            for (int m = 0; m < 4; ++m) res[m] = sb2;
#pragma unroll
            for (int j = 0; j < 16; ++j) {
                float2 jw = sJ[j];               // 1 read / 4 samples
#pragma unroll
                for (int m = 0; m < 4; ++m)
                    res[m] = fmaf(jw.y, fmaxf(acc[m][j] + jw.x, 0.f), res[m]);
            }
            *(float4*)(out + s0) = make_float4(res[0], res[1], res[2], res[3]);
        } else {
            // tail: per-sample path
            for (int m = 0; m < 4; ++m) {
                int s = s0 + m;
                if (s >= B) break;
                float x0 = x[3*s], x1 = x[3*s+1], x2 = x[3*s+2];
                float acc1[16];
#pragma unroll
                for (int j = 0; j < 16; ++j) acc1[j] = 0.f;
#pragma unroll 4
                for (int g = 0; g < 16; ++g) {
                    float4 w = sW1[g];
                    float r0, r1, r2;
                    conv3_relu(x0, x1, x2, w.x, w.y, w.z, w.w, r0, r1, r2);
#pragma unroll
                    for (int jj = 0; jj < 2; ++jj) {
                        int o = 2 * g + jj;
                        float4 u = sU[o];
                        float2 cc = sC[o];
                        float v0 = fmaxf(fmaf(u.y, r0, fmaf(u.z, r1, u.w)), 0.f);
                        float v1 = fmaxf(fmaf(u.x, r0, fmaf(u.y, r1, fmaf(u.z, r2, cc.x))), 0.f);
                        float v2 = fmaxf(fmaf(u.x, r1, fmaf(u.y, r2, cc.y)), 0.f);
                        float so = v0 + v1 + v2;
#pragma unroll
                        for (int k = 0; k < 4; ++k) {
                            float4 f = sFT[o * 4 + k];
                            acc1[4*k+0] = fmaf(f.x, so, acc1[4*k+0]);
                            acc1[4*k+1] = fmaf(f.y, so, acc1[4*k+1]);
                            acc1[4*k+2] = fmaf(f.z, so, acc1[4*k+2]);
                            acc1[4*k+3] = fmaf(f.w, so, acc1[4*k+3]);
                        }
                    }
                }
                float r = sb2;
#pragma unroll
                for (int j = 0; j < 16; ++j) {
                    float2 jw = sJ[j];
                    r = fmaf(jw.y, fmaxf(acc1[j] + jw.x, 0.f), r);
                }
                out[s] = r;
            }
        }
    }
}

// ---------------------------------------------------------------------------
extern "C" void kernel_launch(void* const* d_in, const int* in_sizes, int n_in,
                              void* d_out, int out_size, void* d_ws, size_t ws_size,
                              hipStream_t stream)
{
    const float* x   = (const float*)d_in[0];
    const float* w1  = (const float*)d_in[1];
    const float* b1  = (const float*)d_in[2];
    const float* g1  = (const float*)d_in[3];
    const float* bt1 = (const float*)d_in[4];
    const float* w2  = (const float*)d_in[5];
    const float* b2  = (const float*)d_in[6];
    const float* g2  = (const float*)d_in[7];
    const float* bt2 = (const float*)d_in[8];
    const float* fw1 = (const float*)d_in[9];
    const float* fb1 = (const float*)d_in[10];
    const float* fw2 = (const float*)d_in[11];
    const float* fb2 = (const float*)d_in[12];

    int B = in_sizes[0] / 3;

    // ws floats: accA 16*32=512 | accB 32*64=2048 | wU 128 | wC 64 (=2752)
    float*  ws   = (float*)d_ws;
    float*  accA = ws;                          // 512
    float*  accB = ws + 512;                    // 2048
    float4* wU   = (float4*)(ws + 2560);        // 32 float4 (16B aligned)
    float2* wC   = (float2*)(ws + 2688);        // 32 float2

    float Ninv = 1.0f / (3.0f * (float)B);

    int nb1 = 1024;   // stats1: 1 chunk/thread (saturated)
    int nb2 = 2048;   // stats2: 1 chunk/pair (saturated; was 2 chunks/pair)
    int nchunk = (B + 3) / 4;
    int gridF = (nchunk + 255) / 256;           // 4 samples/thread
    if (gridF > 2048) gridF = 2048;             // B=1M -> 1024 blocks

    // zero the sharded accumulators (ws is poison-filled each iteration)
    hipMemsetAsync(ws, 0, 2560 * sizeof(float), stream);

    k_stats1<<<nb1, 256, 0, stream>>>(x, w1, b1, accA, B);
    k_stats2<<<nb2, 256, 0, stream>>>(x, w1, b1, accA, g1, bt1, w2, b2,
                                      accB, wU, wC, Ninv, B);
    k_final<<<gridF, 256, 0, stream>>>(x, w1, b1, wU, wC, accB, fw1, fb1,
                                       g2, bt2, fw2, fb2, (float*)d_out,
                                       Ninv, B);
}